// Round 1
// baseline (2838.595 us; speedup 1.0000x reference)
//
#include <hip/hip_runtime.h>
#include <hip/hip_bf16.h>
#include <math.h>

#define B_ 4
#define S_ 512
#define DM_ 768
#define L_ 2
#define DI_ 1536
#define DS_ 16
#define KC_ 4
#define DTR_ 48

// h[b,s,d] = x[b,s,0]*w_in[d,0] + b_in[d] + pe[s,d]
__global__ void k_embed(const float* __restrict__ x, const float* __restrict__ w_in,
                        const float* __restrict__ b_in, const float* __restrict__ pe,
                        float* __restrict__ h) {
  int idx = blockIdx.x * 256 + threadIdx.x;
  if (idx >= B_ * S_ * DM_) return;
  int d = idx % DM_;
  int t = idx / DM_;   // b*S+s
  int s = t % S_;
  h[idx] = x[t] * w_in[d] + b_in[d] + pe[s * DM_ + d];
}

// LayerNorm over last dim (DM)
__global__ void k_ln(const float* __restrict__ in, const float* __restrict__ w,
                     const float* __restrict__ b, float* __restrict__ out) {
  __shared__ float red1[4], red2[4];
  __shared__ float s_mu, s_rstd;
  int row = blockIdx.x;
  const float* x = in + (size_t)row * DM_;
  float s1 = 0.f, s2 = 0.f;
  for (int i = threadIdx.x; i < DM_; i += 256) { float v = x[i]; s1 += v; s2 += v * v; }
  for (int off = 32; off; off >>= 1) { s1 += __shfl_down(s1, off); s2 += __shfl_down(s2, off); }
  if ((threadIdx.x & 63) == 0) { red1[threadIdx.x >> 6] = s1; red2[threadIdx.x >> 6] = s2; }
  __syncthreads();
  if (threadIdx.x == 0) {
    float t1 = red1[0] + red1[1] + red1[2] + red1[3];
    float t2 = red2[0] + red2[1] + red2[2] + red2[3];
    float mu = t1 * (1.f / DM_);
    float var = t2 * (1.f / DM_) - mu * mu;
    s_mu = mu;
    s_rstd = rsqrtf(var + 1e-5f);
  }
  __syncthreads();
  float mu = s_mu, rstd = s_rstd;
  for (int i = threadIdx.x; i < DM_; i += 256)
    out[(size_t)row * DM_ + i] = (x[i] - mu) * rstd * w[i] + b[i];
}

// C[m,n] = epi( sum_k A[m,k]*W[n,k] + bias[n] (+ res[m,n]) )
// EPI: 0 none, 1 +residual, 2 gelu(exact), 3 softplus
template <int EPI>
__global__ __launch_bounds__(256)
void k_gemm_nt(const float* __restrict__ A, int lda,
               const float* __restrict__ W, int ldw,
               const float* __restrict__ bias,
               const float* __restrict__ res,
               float* __restrict__ C, int ldc,
               int M, int N, int Kdim) {
  __shared__ float As[16][68];
  __shared__ float Bs[16][68];
  int tx = threadIdx.x & 15;
  int ty = threadIdx.x >> 4;
  int m0 = blockIdx.y * 64;
  int n0 = blockIdx.x * 64;
  float acc[4][4] = {};
  for (int k0 = 0; k0 < Kdim; k0 += 16) {
    for (int i = threadIdx.x; i < 64 * 16; i += 256) {
      int r = i >> 4, c = i & 15;
      int m = m0 + r;
      As[c][r] = (m < M) ? A[(size_t)m * lda + k0 + c] : 0.f;
      int nn = n0 + r;
      Bs[c][r] = (nn < N) ? W[(size_t)nn * ldw + k0 + c] : 0.f;
    }
    __syncthreads();
#pragma unroll
    for (int kk = 0; kk < 16; ++kk) {
      float4 av = *(const float4*)&As[kk][ty * 4];
      float4 bv = *(const float4*)&Bs[kk][tx * 4];
      float a_[4] = {av.x, av.y, av.z, av.w};
      float b_[4] = {bv.x, bv.y, bv.z, bv.w};
#pragma unroll
      for (int i2 = 0; i2 < 4; ++i2)
#pragma unroll
        for (int j = 0; j < 4; ++j)
          acc[i2][j] = fmaf(a_[i2], b_[j], acc[i2][j]);
    }
    __syncthreads();
  }
#pragma unroll
  for (int i2 = 0; i2 < 4; ++i2) {
    int m = m0 + ty * 4 + i2;
    if (m >= M) continue;
#pragma unroll
    for (int j = 0; j < 4; ++j) {
      int nn = n0 + tx * 4 + j;
      if (nn >= N) continue;
      float v = acc[i2][j];
      if (bias) v += bias[nn];
      if (EPI == 1) v += res[(size_t)m * ldc + nn];
      if (EPI == 2) v = 0.5f * v * (1.f + erff(v * 0.70710678118654752f));
      if (EPI == 3) v = (v > 20.f) ? v : log1pf(expf(v));
      C[(size_t)m * ldc + nn] = v;
    }
  }
}

// depthwise causal conv (K=4) + bias + SiLU; xm = xz[..., :DI] (row stride 2*DI)
__global__ void k_conv_silu(const float* __restrict__ xz, const float* __restrict__ cw,
                            const float* __restrict__ cb, float* __restrict__ xc) {
  int idx = blockIdx.x * 256 + threadIdx.x;
  if (idx >= B_ * S_ * DI_) return;
  int d = idx % DI_;
  int t = idx / DI_;
  int s = t % S_;
  int b = t / S_;
  float acc = cb[d];
  const float* base = xz + (size_t)(b * S_) * (2 * DI_) + d;
#pragma unroll
  for (int k = 0; k < KC_; ++k) {
    int ss = s - (KC_ - 1) + k;
    if (ss >= 0) acc = fmaf(base[(size_t)ss * (2 * DI_)], cw[d * KC_ + k], acc);
  }
  xc[idx] = acc / (1.f + expf(-acc));
}

// selective scan: one 16-lane group per (b,d); lane n holds state n
__global__ void k_scan(const float* __restrict__ delta, const float* __restrict__ xc,
                       const float* __restrict__ dbc, const float* __restrict__ A_log,
                       float* __restrict__ y) {
  int g = blockIdx.x * 16 + (threadIdx.x >> 4);
  int n = threadIdx.x & 15;
  int b = g / DI_;
  int d = g - b * DI_;
  float A = -expf(A_log[d * DS_ + n]);
  float h = 0.f;
  const float* drow = delta + (size_t)b * S_ * DI_ + d;
  const float* urow = xc + (size_t)b * S_ * DI_ + d;
  const float* brow = dbc + (size_t)b * S_ * 80 + 48 + n;
  float* yrow = y + (size_t)b * S_ * DI_ + d;
  for (int s = 0; s < S_; ++s) {
    float dl = drow[(size_t)s * DI_];
    float u = urow[(size_t)s * DI_];
    float Bn = brow[(size_t)s * 80];
    float Cn = brow[(size_t)s * 80 + 16];
    h = h * expf(dl * A) + dl * u * Bn;
    float p = h * Cn;
    p += __shfl_xor(p, 1, 16);
    p += __shfl_xor(p, 2, 16);
    p += __shfl_xor(p, 4, 16);
    p += __shfl_xor(p, 8, 16);
    if (n == 0) yrow[(size_t)s * DI_] = p;
  }
}

// y = (y + xc*D) * silu(z), z = xz[..., DI:]
__global__ void k_ygate(float* __restrict__ y, const float* __restrict__ xc,
                        const float* __restrict__ xz, const float* __restrict__ Dv) {
  int idx = blockIdx.x * 256 + threadIdx.x;
  if (idx >= B_ * S_ * DI_) return;
  int d = idx % DI_;
  int t = idx / DI_;
  float z = xz[(size_t)t * (2 * DI_) + DI_ + d];
  float sig = 1.f / (1.f + expf(-z));
  y[idx] = (y[idx] + xc[idx] * Dv[d]) * (z * sig);
}

// out[b] = mean_s( hf[b,s,:] ) . w_head + b_head
__global__ void k_head(const float* __restrict__ hf, const float* __restrict__ wh,
                       const float* __restrict__ bh, float* __restrict__ out) {
  __shared__ float a[4];
  int b = blockIdx.x;
  float acc = 0.f;
  for (int i = threadIdx.x; i < S_ * DM_; i += 256)
    acc += hf[(size_t)b * S_ * DM_ + i] * wh[i % DM_];
  for (int off = 32; off; off >>= 1) acc += __shfl_down(acc, off);
  if ((threadIdx.x & 63) == 0) a[threadIdx.x >> 6] = acc;
  __syncthreads();
  if (threadIdx.x == 0) out[b] = (a[0] + a[1] + a[2] + a[3]) * (1.f / S_) + bh[0];
}

extern "C" void kernel_launch(void* const* d_in, const int* in_sizes, int n_in,
                              void* d_out, int out_size, void* d_ws, size_t ws_size,
                              hipStream_t stream) {
  const float* x        = (const float*)d_in[0];
  const float* w_in     = (const float*)d_in[1];
  const float* b_in     = (const float*)d_in[2];
  const float* pe       = (const float*)d_in[3];
  const float* ln1_w    = (const float*)d_in[4];
  const float* ln1_b    = (const float*)d_in[5];
  const float* w_inproj = (const float*)d_in[6];
  const float* conv_w   = (const float*)d_in[7];
  const float* conv_b   = (const float*)d_in[8];
  const float* w_xproj  = (const float*)d_in[9];
  const float* w_dt     = (const float*)d_in[10];
  const float* b_dt     = (const float*)d_in[11];
  const float* A_log    = (const float*)d_in[12];
  const float* Dv       = (const float*)d_in[13];
  const float* w_outproj= (const float*)d_in[14];
  const float* ln2_w    = (const float*)d_in[15];
  const float* ln2_b    = (const float*)d_in[16];
  const float* ff_w1    = (const float*)d_in[17];
  const float* ff_b1    = (const float*)d_in[18];
  const float* ff_w2    = (const float*)d_in[19];
  const float* ff_b2    = (const float*)d_in[20];
  const float* lnf_w    = (const float*)d_in[21];
  const float* lnf_b    = (const float*)d_in[22];
  const float* w_head   = (const float*)d_in[23];
  const float* b_head   = (const float*)d_in[24];
  float* out = (float*)d_out;

  float* ws = (float*)d_ws;
  float* h    = ws; ws += (size_t)B_ * S_ * DM_;        // 1.57M
  float* xln  = ws; ws += (size_t)B_ * S_ * DM_;        // 1.57M
  float* xz   = ws; ws += (size_t)B_ * S_ * 2 * DI_;    // 6.29M
  float* xc   = ws; ws += (size_t)B_ * S_ * DI_;        // 3.15M
  float* dbc  = ws; ws += (size_t)B_ * S_ * 80;         // 0.16M
  float* dlt  = ws; ws += (size_t)B_ * S_ * DI_;        // 3.15M
  float* yb   = ws; ws += (size_t)B_ * S_ * DI_;        // 3.15M

  dim3 blk(256);
  const int M = B_ * S_;  // 2048

  k_embed<<<(B_ * S_ * DM_ + 255) / 256, blk, 0, stream>>>(x, w_in, b_in, pe, h);

  for (int l = 0; l < L_; ++l) {
    k_ln<<<M, blk, 0, stream>>>(h, ln1_w + l * DM_, ln1_b + l * DM_, xln);

    // xz = xln @ w_inproj^T   (M x 3072, K=768)
    k_gemm_nt<0><<<dim3((2 * DI_) / 64, M / 64), blk, 0, stream>>>(
        xln, DM_, w_inproj + (size_t)l * 2 * DI_ * DM_, DM_, nullptr, nullptr,
        xz, 2 * DI_, M, 2 * DI_, DM_);

    k_conv_silu<<<(B_ * S_ * DI_ + 255) / 256, blk, 0, stream>>>(
        xz, conv_w + l * DI_ * KC_, conv_b + l * DI_, xc);

    // dbc = xc @ w_xproj^T    (M x 80, K=1536)
    k_gemm_nt<0><<<dim3(2, M / 64), blk, 0, stream>>>(
        xc, DI_, w_xproj + (size_t)l * 80 * DI_, DI_, nullptr, nullptr,
        dbc, 80, M, 80, DI_);

    // delta = softplus(dt @ w_dt^T + b_dt)   (M x 1536, K=48, A from dbc cols 0..47)
    k_gemm_nt<3><<<dim3(DI_ / 64, M / 64), blk, 0, stream>>>(
        dbc, 80, w_dt + (size_t)l * DI_ * DTR_, DTR_, b_dt + l * DI_, nullptr,
        dlt, DI_, M, DI_, DTR_);

    k_scan<<<(B_ * DI_) / 16, blk, 0, stream>>>(
        dlt, xc, dbc, A_log + (size_t)l * DI_ * DS_, yb);

    k_ygate<<<(B_ * S_ * DI_ + 255) / 256, blk, 0, stream>>>(
        yb, xc, xz, Dv + l * DI_);

    // h += yb @ w_outproj^T   (M x 768, K=1536)
    k_gemm_nt<1><<<dim3(DM_ / 64, M / 64), blk, 0, stream>>>(
        yb, DI_, w_outproj + (size_t)l * DM_ * DI_, DI_, nullptr, h,
        h, DM_, M, DM_, DI_);

    k_ln<<<M, blk, 0, stream>>>(h, ln2_w + l * DM_, ln2_b + l * DM_, xln);

    // ffh = gelu(xln @ ff_w1^T + b1)  (M x 1536, K=768) — reuse xz buffer
    k_gemm_nt<2><<<dim3((2 * DM_) / 64, M / 64), blk, 0, stream>>>(
        xln, DM_, ff_w1 + (size_t)l * 2 * DM_ * DM_, DM_, ff_b1 + l * 2 * DM_, nullptr,
        xz, 2 * DM_, M, 2 * DM_, DM_);

    // h += ffh @ ff_w2^T + b2  (M x 768, K=1536)
    k_gemm_nt<1><<<dim3(DM_ / 64, M / 64), blk, 0, stream>>>(
        xz, 2 * DM_, ff_w2 + (size_t)l * DM_ * 2 * DM_, 2 * DM_, ff_b2 + l * DM_, h,
        h, DM_, M, DM_, DI_ /*K=1536*/);
  }

  k_ln<<<M, blk, 0, stream>>>(h, lnf_w, lnf_b, xln);
  k_head<<<B_, blk, 0, stream>>>(xln, w_head, b_head, out);
}

// Round 2
// 1073.130 us; speedup vs baseline: 2.6452x; 2.6452x over previous
//
#include <hip/hip_runtime.h>
#include <hip/hip_bf16.h>
#include <math.h>

#define B_ 4
#define S_ 512
#define DM_ 768
#define L_ 2
#define DI_ 1536
#define DS_ 16
#define KC_ 4
#define DTR_ 48

typedef __hip_bfloat16 bf16;
typedef __attribute__((ext_vector_type(8))) short short8;
typedef __attribute__((ext_vector_type(4))) float f32x4;

#define GLDS16(g, l) __builtin_amdgcn_global_load_lds( \
    (const __attribute__((address_space(1))) void*)(g), \
    (__attribute__((address_space(3))) void*)(l), 16, 0, 0)

// ---------------- elementwise / small kernels ----------------

__global__ void k_embed(const float* __restrict__ x, const float* __restrict__ w_in,
                        const float* __restrict__ b_in, const float* __restrict__ pe,
                        float* __restrict__ h) {
  int idx = blockIdx.x * 256 + threadIdx.x;
  if (idx >= B_ * S_ * DM_) return;
  int d = idx % DM_;
  int t = idx / DM_;
  int s = t % S_;
  h[idx] = x[t] * w_in[d] + b_in[d] + pe[s * DM_ + d];
}

// LayerNorm over DM; fp32 in, bf16 out
__global__ void k_ln(const float* __restrict__ in, const float* __restrict__ w,
                     const float* __restrict__ b, bf16* __restrict__ out) {
  __shared__ float red1[4], red2[4];
  __shared__ float s_mu, s_rstd;
  int row = blockIdx.x;
  const float* x = in + (size_t)row * DM_;
  float s1 = 0.f, s2 = 0.f;
  for (int i = threadIdx.x; i < DM_; i += 256) { float v = x[i]; s1 += v; s2 += v * v; }
  for (int off = 32; off; off >>= 1) { s1 += __shfl_down(s1, off); s2 += __shfl_down(s2, off); }
  if ((threadIdx.x & 63) == 0) { red1[threadIdx.x >> 6] = s1; red2[threadIdx.x >> 6] = s2; }
  __syncthreads();
  if (threadIdx.x == 0) {
    float t1 = red1[0] + red1[1] + red1[2] + red1[3];
    float t2 = red2[0] + red2[1] + red2[2] + red2[3];
    float mu = t1 * (1.f / DM_);
    float var = t2 * (1.f / DM_) - mu * mu;
    s_mu = mu;
    s_rstd = rsqrtf(var + 1e-5f);
  }
  __syncthreads();
  float mu = s_mu, rstd = s_rstd;
  for (int i = threadIdx.x; i < DM_; i += 256)
    out[(size_t)row * DM_ + i] = __float2bfloat16((x[i] - mu) * rstd * w[i] + b[i]);
}

__global__ void k_cast(const float* __restrict__ src, bf16* __restrict__ dst, int n) {
  int i = blockIdx.x * 256 + threadIdx.x;
  if (i < n) dst[i] = __float2bfloat16(src[i]);
}

// w_xproj (L,80,1536) -> per-layer [128][1536] bf16, rows 80..127 zero
__global__ void k_cast_xproj(const float* __restrict__ src, bf16* __restrict__ dst) {
  int i = blockIdx.x * 256 + threadIdx.x;
  if (i >= 2 * 128 * 1536) return;
  int col = i % 1536;
  int row = (i / 1536) & 127;
  int l = i / (128 * 1536);
  float v = (row < 80) ? src[((size_t)l * 80 + row) * 1536 + col] : 0.f;
  dst[i] = __float2bfloat16(v);
}

// w_dt (L,1536,48) -> [L][1536][64] bf16, cols 48..63 zero
__global__ void k_cast_dt(const float* __restrict__ src, bf16* __restrict__ dst) {
  int i = blockIdx.x * 256 + threadIdx.x;
  if (i >= 2 * 1536 * 64) return;
  int col = i & 63;
  int r = (i >> 6) % 1536;
  int l = i / (1536 * 64);
  float v = (col < 48) ? src[((size_t)l * 1536 + r) * 48 + col] : 0.f;
  dst[i] = __float2bfloat16(v);
}

// depthwise causal conv (K=4) + bias + SiLU; writes fp32 xc and bf16 xcb
__global__ void k_conv_silu(const float* __restrict__ xz, const float* __restrict__ cw,
                            const float* __restrict__ cb, float* __restrict__ xc,
                            bf16* __restrict__ xcb) {
  int idx = blockIdx.x * 256 + threadIdx.x;
  if (idx >= B_ * S_ * DI_) return;
  int d = idx % DI_;
  int t = idx / DI_;
  int s = t % S_;
  int b = t / S_;
  float acc = cb[d];
  const float* base = xz + (size_t)(b * S_) * (2 * DI_) + d;
#pragma unroll
  for (int k = 0; k < KC_; ++k) {
    int ss = s - (KC_ - 1) + k;
    if (ss >= 0) acc = fmaf(base[(size_t)ss * (2 * DI_)], cw[d * KC_ + k], acc);
  }
  float v = acc / (1.f + expf(-acc));
  xc[idx] = v;
  xcb[idx] = __float2bfloat16(v);
}

// selective scan: one 16-lane group per (b,d); lane n holds state n
__global__ void k_scan(const float* __restrict__ delta, const float* __restrict__ xc,
                       const float* __restrict__ bc, const float* __restrict__ A_log,
                       float* __restrict__ y) {
  int g = blockIdx.x * 16 + (threadIdx.x >> 4);
  int n = threadIdx.x & 15;
  int b = g / DI_;
  int d = g - b * DI_;
  float A = -expf(A_log[d * DS_ + n]);
  float h = 0.f;
  const float* drow = delta + (size_t)b * S_ * DI_ + d;
  const float* urow = xc + (size_t)b * S_ * DI_ + d;
  const float* brow = bc + (size_t)b * S_ * 32 + n;
  float* yrow = y + (size_t)b * S_ * DI_ + d;
  for (int s = 0; s < S_; ++s) {
    float dl = drow[(size_t)s * DI_];
    float u = urow[(size_t)s * DI_];
    float Bn = brow[(size_t)s * 32];
    float Cn = brow[(size_t)s * 32 + 16];
    h = h * expf(dl * A) + dl * u * Bn;
    float p = h * Cn;
    p += __shfl_xor(p, 1, 16);
    p += __shfl_xor(p, 2, 16);
    p += __shfl_xor(p, 4, 16);
    p += __shfl_xor(p, 8, 16);
    if (n == 0) yrow[(size_t)s * DI_] = p;
  }
}

// yb16 = bf16( (y + xc*D) * silu(z) )
__global__ void k_ygate(const float* __restrict__ y, const float* __restrict__ xc,
                        const float* __restrict__ xz, const float* __restrict__ Dv,
                        bf16* __restrict__ yb16) {
  int idx = blockIdx.x * 256 + threadIdx.x;
  if (idx >= B_ * S_ * DI_) return;
  int d = idx % DI_;
  int t = idx / DI_;
  float z = xz[(size_t)t * (2 * DI_) + DI_ + d];
  float sig = 1.f / (1.f + expf(-z));
  yb16[idx] = __float2bfloat16((y[idx] + xc[idx] * Dv[d]) * (z * sig));
}

// head stage 1: block (j,b) reduces rows s in [j*32, j*32+32)
__global__ void k_head1(const bf16* __restrict__ hf, const float* __restrict__ wh,
                        float* __restrict__ partial) {
  __shared__ float red[4];
  int b = blockIdx.y, j = blockIdx.x;
  const bf16* base = hf + ((size_t)b * S_ + j * 32) * DM_;
  float acc = 0.f;
  for (int i = threadIdx.x; i < 32 * DM_; i += 256) {
    int d = i - (i / DM_) * DM_;
    acc += __bfloat162float(base[i]) * wh[d];
  }
  for (int off = 32; off; off >>= 1) acc += __shfl_down(acc, off);
  if ((threadIdx.x & 63) == 0) red[threadIdx.x >> 6] = acc;
  __syncthreads();
  if (threadIdx.x == 0)
    partial[b * 16 + j] = red[0] + red[1] + red[2] + red[3];
}

__global__ void k_head2(const float* __restrict__ partial, const float* __restrict__ bh,
                        float* __restrict__ out) {
  int b = threadIdx.x;
  if (b < B_) {
    float acc = 0.f;
    for (int j = 0; j < 16; ++j) acc += partial[b * 16 + j];
    out[b] = acc * (1.f / S_) + bh[0];
  }
}

// ---------------- MFMA GEMM ----------------
// C[m,n] = epi( sum_k A[m,k]*W[n,k] ), A,W bf16 row-major (K contiguous).
// 128x128 tile, BK=32, 256 threads = 4 waves in 2x2, each wave 64x64 (4x4 frags).
// EPI: 0 plain f32 out; 1 f32 out + bias? + res; 2 bias+gelu -> bf16 out;
//      3 bias+softplus -> f32 out; 4 xproj split (dtp bf16 / bc f32)
template <int EPI>
__global__ __launch_bounds__(256)
void k_gemm_mfma(const bf16* __restrict__ A, int lda,
                 const bf16* __restrict__ W, int ldw,
                 const float* __restrict__ bias,
                 const float* __restrict__ res,
                 void* __restrict__ out1, void* __restrict__ out2,
                 int ldc, int N, int Kdim) {
  __shared__ short As[128 * 32];
  __shared__ short Bs[128 * 32];
  int m0 = blockIdx.y * 128;
  int n0 = blockIdx.x * 128;
  int wid = threadIdx.x >> 6;
  int lane = threadIdx.x & 63;
  int wm = wid >> 1, wn = wid & 1;
  int lr = lane & 15;
  int kb = (lane >> 4) * 8;

  f32x4 acc[4][4];
#pragma unroll
  for (int i = 0; i < 4; ++i)
#pragma unroll
    for (int j = 0; j < 4; ++j) {
      acc[i][j][0] = 0.f; acc[i][j][1] = 0.f; acc[i][j][2] = 0.f; acc[i][j][3] = 0.f;
    }

  for (int k0 = 0; k0 < Kdim; k0 += 32) {
#pragma unroll
    for (int c0 = 0; c0 < 2; ++c0) {
      int c = c0 * 256 + threadIdx.x;
      GLDS16(A + (size_t)(m0 + (c >> 2)) * lda + k0 + (c & 3) * 8, (char*)As + c * 16);
    }
#pragma unroll
    for (int c0 = 0; c0 < 2; ++c0) {
      int c = c0 * 256 + threadIdx.x;
      GLDS16(W + (size_t)(n0 + (c >> 2)) * ldw + k0 + (c & 3) * 8, (char*)Bs + c * 16);
    }
    __syncthreads();

    short8 a[4], b[4];
#pragma unroll
    for (int f = 0; f < 4; ++f) {
      a[f] = *(const short8*)&As[(wm * 64 + f * 16 + lr) * 32 + kb];
      b[f] = *(const short8*)&Bs[(wn * 64 + f * 16 + lr) * 32 + kb];
    }
#pragma unroll
    for (int i = 0; i < 4; ++i)
#pragma unroll
      for (int j = 0; j < 4; ++j)
        acc[i][j] = __builtin_amdgcn_mfma_f32_16x16x32_bf16(a[i], b[j], acc[i][j], 0, 0, 0);
    __syncthreads();
  }

  // epilogue: D col = lane&15, row = (lane>>4)*4 + q
#pragma unroll
  for (int i = 0; i < 4; ++i) {
#pragma unroll
    for (int j = 0; j < 4; ++j) {
      int n = n0 + wn * 64 + j * 16 + (lane & 15);
#pragma unroll
      for (int q = 0; q < 4; ++q) {
        int m = m0 + wm * 64 + i * 16 + (lane >> 4) * 4 + q;
        float v = acc[i][j][q];
        if (EPI == 0) {
          if (n < N) ((float*)out1)[(size_t)m * ldc + n] = v;
        } else if (EPI == 1) {
          if (n < N) {
            if (bias) v += bias[n];
            ((float*)out1)[(size_t)m * ldc + n] = v + res[(size_t)m * ldc + n];
          }
        } else if (EPI == 2) {
          if (n < N) {
            v += bias[n];
            v = 0.5f * v * (1.f + erff(v * 0.70710678118654752f));
            ((bf16*)out1)[(size_t)m * ldc + n] = __float2bfloat16(v);
          }
        } else if (EPI == 3) {
          if (n < N) {
            v += bias[n];
            v = (v > 20.f) ? v : log1pf(expf(v));
            ((float*)out1)[(size_t)m * ldc + n] = v;
          }
        } else if (EPI == 4) {
          if (n < 48) {
            ((bf16*)out1)[(size_t)m * 64 + n] = __float2bfloat16(v);
          } else if (n < 80) {
            ((float*)out2)[(size_t)m * 32 + (n - 48)] = v;
          } else if (n < 96) {
            ((bf16*)out1)[(size_t)m * 64 + (n - 32)] = __float2bfloat16(0.f);
          }
        }
      }
    }
  }
}

// ---------------- launch ----------------

extern "C" void kernel_launch(void* const* d_in, const int* in_sizes, int n_in,
                              void* d_out, int out_size, void* d_ws, size_t ws_size,
                              hipStream_t stream) {
  const float* x        = (const float*)d_in[0];
  const float* w_in     = (const float*)d_in[1];
  const float* b_in     = (const float*)d_in[2];
  const float* pe       = (const float*)d_in[3];
  const float* ln1_w    = (const float*)d_in[4];
  const float* ln1_b    = (const float*)d_in[5];
  const float* w_inproj = (const float*)d_in[6];
  const float* conv_w   = (const float*)d_in[7];
  const float* conv_b   = (const float*)d_in[8];
  const float* w_xproj  = (const float*)d_in[9];
  const float* w_dt     = (const float*)d_in[10];
  const float* b_dt     = (const float*)d_in[11];
  const float* A_log    = (const float*)d_in[12];
  const float* Dv       = (const float*)d_in[13];
  const float* w_outproj= (const float*)d_in[14];
  const float* ln2_w    = (const float*)d_in[15];
  const float* ln2_b    = (const float*)d_in[16];
  const float* ff_w1    = (const float*)d_in[17];
  const float* ff_b1    = (const float*)d_in[18];
  const float* ff_w2    = (const float*)d_in[19];
  const float* ff_b2    = (const float*)d_in[20];
  const float* lnf_w    = (const float*)d_in[21];
  const float* lnf_b    = (const float*)d_in[22];
  const float* w_head   = (const float*)d_in[23];
  const float* b_head   = (const float*)d_in[24];
  float* out = (float*)d_out;

  const int M = B_ * S_;  // 2048

  // fp32 workspace
  float* wsf = (float*)d_ws;
  float* h    = wsf; wsf += (size_t)M * DM_;          // 1.57M
  float* xz   = wsf; wsf += (size_t)M * 2 * DI_;      // 6.29M
  float* xc   = wsf; wsf += (size_t)M * DI_;          // 3.15M
  float* bc   = wsf; wsf += (size_t)M * 32;           // 65K
  float* dlt  = wsf; wsf += (size_t)M * DI_;          // 3.15M
  float* y    = wsf; wsf += (size_t)M * DI_;          // 3.15M
  float* part = wsf; wsf += 64;
  // bf16 workspace
  bf16* wsb = (bf16*)wsf;
  bf16* xln16 = wsb; wsb += (size_t)M * DM_;
  bf16* xcb   = wsb; wsb += (size_t)M * DI_;
  bf16* dtp   = wsb; wsb += (size_t)M * 64;
  bf16* yb16  = wsb; wsb += (size_t)M * DI_;
  bf16* ffh16 = wsb; wsb += (size_t)M * DI_;
  bf16* wip   = wsb; wsb += (size_t)L_ * 2 * DI_ * DM_;   // 4.72M
  bf16* wxp   = wsb; wsb += (size_t)L_ * 128 * DI_;       // 0.39M
  bf16* wdtp  = wsb; wsb += (size_t)L_ * DI_ * 64;        // 0.20M
  bf16* wop   = wsb; wsb += (size_t)L_ * DM_ * DI_;       // 2.36M
  bf16* wf1   = wsb; wsb += (size_t)L_ * 2 * DM_ * DM_;   // 2.36M
  bf16* wf2   = wsb; wsb += (size_t)L_ * DM_ * 2 * DM_;   // 2.36M

  dim3 blk(256);

  // weight casts (once per launch)
  {
    int n;
    n = L_ * 2 * DI_ * DM_;  k_cast<<<(n + 255) / 256, blk, 0, stream>>>(w_inproj, wip, n);
    n = L_ * DM_ * DI_;      k_cast<<<(n + 255) / 256, blk, 0, stream>>>(w_outproj, wop, n);
    n = L_ * 2 * DM_ * DM_;  k_cast<<<(n + 255) / 256, blk, 0, stream>>>(ff_w1, wf1, n);
    n = L_ * DM_ * 2 * DM_;  k_cast<<<(n + 255) / 256, blk, 0, stream>>>(ff_w2, wf2, n);
    n = L_ * 128 * DI_;      k_cast_xproj<<<(n + 255) / 256, blk, 0, stream>>>(w_xproj, wxp);
    n = L_ * DI_ * 64;       k_cast_dt<<<(n + 255) / 256, blk, 0, stream>>>(w_dt, wdtp);
  }

  k_embed<<<(B_ * S_ * DM_ + 255) / 256, blk, 0, stream>>>(x, w_in, b_in, pe, h);

  for (int l = 0; l < L_; ++l) {
    k_ln<<<M, blk, 0, stream>>>(h, ln1_w + l * DM_, ln1_b + l * DM_, xln16);

    // xz = xln @ w_inproj^T   (M x 3072, K=768)
    k_gemm_mfma<0><<<dim3(2 * DI_ / 128, M / 128), blk, 0, stream>>>(
        xln16, DM_, wip + (size_t)l * 2 * DI_ * DM_, DM_, nullptr, nullptr,
        xz, nullptr, 2 * DI_, 2 * DI_, DM_);

    k_conv_silu<<<(B_ * S_ * DI_ + 255) / 256, blk, 0, stream>>>(
        xz, conv_w + l * DI_ * KC_, conv_b + l * DI_, xc, xcb);

    // xproj: dtp (bf16, K-padded to 64) + bc (f32)   (M x 96 eff, K=1536)
    k_gemm_mfma<4><<<dim3(1, M / 128), blk, 0, stream>>>(
        xcb, DI_, wxp + (size_t)l * 128 * DI_, DI_, nullptr, nullptr,
        dtp, bc, 0, 96, DI_);

    // delta = softplus(dtp @ wdtp^T + b_dt)   (M x 1536, K=64)
    k_gemm_mfma<3><<<dim3(DI_ / 128, M / 128), blk, 0, stream>>>(
        dtp, 64, wdtp + (size_t)l * DI_ * 64, 64, b_dt + l * DI_, nullptr,
        dlt, nullptr, DI_, DI_, 64);

    k_scan<<<(B_ * DI_) / 16, blk, 0, stream>>>(
        dlt, xc, bc, A_log + (size_t)l * DI_ * DS_, y);

    k_ygate<<<(B_ * S_ * DI_ + 255) / 256, blk, 0, stream>>>(
        y, xc, xz, Dv + l * DI_, yb16);

    // h += yb @ w_outproj^T   (M x 768, K=1536)
    k_gemm_mfma<1><<<dim3(DM_ / 128, M / 128), blk, 0, stream>>>(
        yb16, DI_, wop + (size_t)l * DM_ * DI_, DI_, nullptr, h,
        h, nullptr, DM_, DM_, DI_);

    k_ln<<<M, blk, 0, stream>>>(h, ln2_w + l * DM_, ln2_b + l * DM_, xln16);

    // ffh = gelu(xln @ ff_w1^T + b1) -> bf16  (M x 1536, K=768)
    k_gemm_mfma<2><<<dim3(2 * DM_ / 128, M / 128), blk, 0, stream>>>(
        xln16, DM_, wf1 + (size_t)l * 2 * DM_ * DM_, DM_, ff_b1 + l * 2 * DM_, nullptr,
        ffh16, nullptr, 2 * DM_, 2 * DM_, DM_);

    // h += ffh @ ff_w2^T + b2   (M x 768, K=1536)
    k_gemm_mfma<1><<<dim3(DM_ / 128, M / 128), blk, 0, stream>>>(
        ffh16, 2 * DM_, wf2 + (size_t)l * DM_ * 2 * DM_, 2 * DM_, ff_b2 + l * DM_, h,
        h, nullptr, DM_, DM_, DI_);
  }

  k_ln<<<M, blk, 0, stream>>>(h, lnf_w, lnf_b, xln16);
  k_head1<<<dim3(16, B_), blk, 0, stream>>>(xln16, w_head, part);
  k_head2<<<1, 64, 0, stream>>>(part, b_head, out);
}

// Round 3
// 864.929 us; speedup vs baseline: 3.2819x; 1.2407x over previous
//
#include <hip/hip_runtime.h>
#include <hip/hip_bf16.h>
#include <math.h>

#define B_ 4
#define S_ 512
#define DM_ 768
#define L_ 2
#define DI_ 1536
#define DS_ 16
#define KC_ 4
#define DTR_ 48
#define TCH 64

typedef __hip_bfloat16 bf16;
typedef __attribute__((ext_vector_type(8))) short short8;
typedef __attribute__((ext_vector_type(4))) float f32x4;

#define GLDS16(g, l) __builtin_amdgcn_global_load_lds( \
    (const __attribute__((address_space(1))) void*)(g), \
    (__attribute__((address_space(3))) void*)(l), 16, 0, 0)

// ---------------- elementwise / small kernels ----------------

__global__ void k_embed(const float* __restrict__ x, const float* __restrict__ w_in,
                        const float* __restrict__ b_in, const float* __restrict__ pe,
                        float* __restrict__ h) {
  int idx = blockIdx.x * 256 + threadIdx.x;
  if (idx >= B_ * S_ * DM_) return;
  int d = idx % DM_;
  int t = idx / DM_;
  int s = t % S_;
  h[idx] = x[t] * w_in[d] + b_in[d] + pe[s * DM_ + d];
}

// LayerNorm over DM; fp32 in, bf16 out
__global__ void k_ln(const float* __restrict__ in, const float* __restrict__ w,
                     const float* __restrict__ b, bf16* __restrict__ out) {
  __shared__ float red1[4], red2[4];
  __shared__ float s_mu, s_rstd;
  int row = blockIdx.x;
  const float* x = in + (size_t)row * DM_;
  float s1 = 0.f, s2 = 0.f;
  for (int i = threadIdx.x; i < DM_; i += 256) { float v = x[i]; s1 += v; s2 += v * v; }
  for (int off = 32; off; off >>= 1) { s1 += __shfl_down(s1, off); s2 += __shfl_down(s2, off); }
  if ((threadIdx.x & 63) == 0) { red1[threadIdx.x >> 6] = s1; red2[threadIdx.x >> 6] = s2; }
  __syncthreads();
  if (threadIdx.x == 0) {
    float t1 = red1[0] + red1[1] + red1[2] + red1[3];
    float t2 = red2[0] + red2[1] + red2[2] + red2[3];
    float mu = t1 * (1.f / DM_);
    float var = t2 * (1.f / DM_) - mu * mu;
    s_mu = mu;
    s_rstd = rsqrtf(var + 1e-5f);
  }
  __syncthreads();
  float mu = s_mu, rstd = s_rstd;
  for (int i = threadIdx.x; i < DM_; i += 256)
    out[(size_t)row * DM_ + i] = __float2bfloat16((x[i] - mu) * rstd * w[i] + b[i]);
}

__global__ void k_cast(const float* __restrict__ src, bf16* __restrict__ dst, int n) {
  int i = blockIdx.x * 256 + threadIdx.x;
  if (i < n) dst[i] = __float2bfloat16(src[i]);
}

// w_xproj (L,80,1536) -> per-layer [128][1536] bf16, rows 80..127 zero
__global__ void k_cast_xproj(const float* __restrict__ src, bf16* __restrict__ dst) {
  int i = blockIdx.x * 256 + threadIdx.x;
  if (i >= 2 * 128 * 1536) return;
  int col = i % 1536;
  int row = (i / 1536) & 127;
  int l = i / (128 * 1536);
  float v = (row < 80) ? src[((size_t)l * 80 + row) * 1536 + col] : 0.f;
  dst[i] = __float2bfloat16(v);
}

// w_dt (L,1536,48) -> [L][1536][64] bf16, cols 48..63 zero
__global__ void k_cast_dt(const float* __restrict__ src, bf16* __restrict__ dst) {
  int i = blockIdx.x * 256 + threadIdx.x;
  if (i >= 2 * 1536 * 64) return;
  int col = i & 63;
  int r = (i >> 6) % 1536;
  int l = i / (1536 * 64);
  float v = (col < 48) ? src[((size_t)l * 1536 + r) * 48 + col] : 0.f;
  dst[i] = __float2bfloat16(v);
}

// depthwise causal conv (K=4) + bias + SiLU; writes fp32 xc and bf16 xcb
__global__ void k_conv_silu(const float* __restrict__ xz, const float* __restrict__ cw,
                            const float* __restrict__ cb, float* __restrict__ xc,
                            bf16* __restrict__ xcb) {
  int idx = blockIdx.x * 256 + threadIdx.x;
  if (idx >= B_ * S_ * DI_) return;
  int d = idx % DI_;
  int t = idx / DI_;
  int s = t % S_;
  int b = t / S_;
  float acc = cb[d];
  const float* base = xz + (size_t)(b * S_) * (2 * DI_) + d;
#pragma unroll
  for (int k = 0; k < KC_; ++k) {
    int ss = s - (KC_ - 1) + k;
    if (ss >= 0) acc = fmaf(base[(size_t)ss * (2 * DI_)], cw[d * KC_ + k], acc);
  }
  float v = acc / (1.f + expf(-acc));
  xc[idx] = v;
  xcb[idx] = __float2bfloat16(v);
}

// ---------------- selective scan v2: LDS-chunked, double-buffered, fused gate ----
// block = (b, 16 consecutive d); group g handles d = d0+g, lane n holds state n.
// y_out = bf16( (scan_out + u*D) * silu(z) )
__global__ __launch_bounds__(256)
void k_scan2(const float* __restrict__ delta, const float* __restrict__ xc,
             const float* __restrict__ bc, const float* __restrict__ A_log,
             const float* __restrict__ xz, const float* __restrict__ Dv,
             bf16* __restrict__ yb16) {
  __shared__ float sD[2][TCH][16];
  __shared__ float sU[2][TCH][16];
  __shared__ float sZ[2][TCH][16];
  __shared__ float sBC[2][TCH][32];

  int b = blockIdx.y;
  int d0 = blockIdx.x * 16;
  int grp = threadIdx.x >> 4;
  int n = threadIdx.x & 15;
  int d = d0 + grp;

  float A = -expf(A_log[d * DS_ + n]);
  float Dd = Dv[d];
  float h = 0.f;

  const float* dbase = delta + (size_t)b * S_ * DI_ + d0;
  const float* ubase = xc + (size_t)b * S_ * DI_ + d0;
  const float* zbase = xz + (size_t)b * S_ * (2 * DI_) + DI_ + d0;
  const char* bcbase = (const char*)(bc + (size_t)b * S_ * 32);
  bf16* ybase = yb16 + (size_t)b * S_ * DI_ + d0;

  int w = threadIdx.x >> 6, l = threadIdx.x & 63;

#define STAGE(buf, c)                                                              \
  {                                                                                \
    int s0 = (c) * TCH;                                                            \
    int sr = w * 16 + (l >> 2);                                                    \
    int col = (l & 3) * 4;                                                         \
    GLDS16(dbase + (size_t)(s0 + sr) * DI_ + col, (char*)&sD[buf][0][0] + (w * 64 + l) * 16); \
    GLDS16(ubase + (size_t)(s0 + sr) * DI_ + col, (char*)&sU[buf][0][0] + (w * 64 + l) * 16); \
    GLDS16(zbase + (size_t)(s0 + sr) * (2 * DI_) + col, (char*)&sZ[buf][0][0] + (w * 64 + l) * 16); \
    GLDS16(bcbase + (size_t)s0 * 128 + w * 2048 + l * 16, (char*)&sBC[buf][0][0] + w * 2048 + l * 16); \
    GLDS16(bcbase + (size_t)s0 * 128 + w * 2048 + 1024 + l * 16, (char*)&sBC[buf][0][0] + w * 2048 + 1024 + l * 16); \
  }

  STAGE(0, 0);
  __syncthreads();

  const int NC = S_ / TCH;
  for (int c = 0; c < NC; ++c) {
    if (c + 1 < NC) STAGE((c + 1) & 1, c + 1);
    int buf = c & 1;
#pragma unroll 8
    for (int s = 0; s < TCH; ++s) {
      float dl = sD[buf][s][grp];
      float u = sU[buf][s][grp];
      float Bn = sBC[buf][s][n];
      float Cn = sBC[buf][s][16 + n];
      h = h * __expf(dl * A) + dl * u * Bn;
      float p = h * Cn;
      p += __shfl_xor(p, 1, 16);
      p += __shfl_xor(p, 2, 16);
      p += __shfl_xor(p, 4, 16);
      p += __shfl_xor(p, 8, 16);
      if (n == 0) {
        float z = sZ[buf][s][grp];
        float sig = 1.f / (1.f + __expf(-z));
        ybase[(size_t)(c * TCH + s) * DI_ + grp] =
            __float2bfloat16((p + u * Dd) * (z * sig));
      }
    }
    __syncthreads();
  }
#undef STAGE
}

// head stage 1: block (j,b) reduces rows s in [j*32, j*32+32)
__global__ void k_head1(const bf16* __restrict__ hf, const float* __restrict__ wh,
                        float* __restrict__ partial) {
  __shared__ float red[4];
  int b = blockIdx.y, j = blockIdx.x;
  const bf16* base = hf + ((size_t)b * S_ + j * 32) * DM_;
  float acc = 0.f;
  for (int i = threadIdx.x; i < 32 * DM_; i += 256) {
    int dd = i - (i / DM_) * DM_;
    acc += __bfloat162float(base[i]) * wh[dd];
  }
  for (int off = 32; off; off >>= 1) acc += __shfl_down(acc, off);
  if ((threadIdx.x & 63) == 0) red[threadIdx.x >> 6] = acc;
  __syncthreads();
  if (threadIdx.x == 0)
    partial[b * 16 + j] = red[0] + red[1] + red[2] + red[3];
}

__global__ void k_head2(const float* __restrict__ partial, const float* __restrict__ bh,
                        float* __restrict__ out) {
  int b = threadIdx.x;
  if (b < B_) {
    float acc = 0.f;
    for (int j = 0; j < 16; ++j) acc += partial[b * 16 + j];
    out[b] = acc * (1.f / S_) + bh[0];
  }
}

// ---------------- MFMA GEMM ----------------
// C[m,n] = epi( sum_k A[m,k]*W[n,k] ), A,W bf16 row-major (K contiguous).
// 128x128 tile, BK=32, 256 threads = 4 waves in 2x2, each wave 64x64 (4x4 frags).
template <int EPI>
__global__ __launch_bounds__(256)
void k_gemm_mfma(const bf16* __restrict__ A, int lda,
                 const bf16* __restrict__ W, int ldw,
                 const float* __restrict__ bias,
                 const float* __restrict__ res,
                 void* __restrict__ out1, void* __restrict__ out2,
                 int ldc, int N, int Kdim) {
  __shared__ short As[128 * 32];
  __shared__ short Bs[128 * 32];
  int m0 = blockIdx.y * 128;
  int n0 = blockIdx.x * 128;
  int wid = threadIdx.x >> 6;
  int lane = threadIdx.x & 63;
  int wm = wid >> 1, wn = wid & 1;
  int lr = lane & 15;
  int kb = (lane >> 4) * 8;

  f32x4 acc[4][4];
#pragma unroll
  for (int i = 0; i < 4; ++i)
#pragma unroll
    for (int j = 0; j < 4; ++j) {
      acc[i][j][0] = 0.f; acc[i][j][1] = 0.f; acc[i][j][2] = 0.f; acc[i][j][3] = 0.f;
    }

  for (int k0 = 0; k0 < Kdim; k0 += 32) {
#pragma unroll
    for (int c0 = 0; c0 < 2; ++c0) {
      int c = c0 * 256 + threadIdx.x;
      GLDS16(A + (size_t)(m0 + (c >> 2)) * lda + k0 + (c & 3) * 8, (char*)As + c * 16);
    }
#pragma unroll
    for (int c0 = 0; c0 < 2; ++c0) {
      int c = c0 * 256 + threadIdx.x;
      GLDS16(W + (size_t)(n0 + (c >> 2)) * ldw + k0 + (c & 3) * 8, (char*)Bs + c * 16);
    }
    __syncthreads();

    short8 a[4], b[4];
#pragma unroll
    for (int f = 0; f < 4; ++f) {
      a[f] = *(const short8*)&As[(wm * 64 + f * 16 + lr) * 32 + kb];
      b[f] = *(const short8*)&Bs[(wn * 64 + f * 16 + lr) * 32 + kb];
    }
#pragma unroll
    for (int i = 0; i < 4; ++i)
#pragma unroll
      for (int j = 0; j < 4; ++j)
        acc[i][j] = __builtin_amdgcn_mfma_f32_16x16x32_bf16(a[i], b[j], acc[i][j], 0, 0, 0);
    __syncthreads();
  }

#pragma unroll
  for (int i = 0; i < 4; ++i) {
#pragma unroll
    for (int j = 0; j < 4; ++j) {
      int n = n0 + wn * 64 + j * 16 + (lane & 15);
#pragma unroll
      for (int q = 0; q < 4; ++q) {
        int m = m0 + wm * 64 + i * 16 + (lane >> 4) * 4 + q;
        float v = acc[i][j][q];
        if (EPI == 0) {
          if (n < N) ((float*)out1)[(size_t)m * ldc + n] = v;
        } else if (EPI == 1) {
          if (n < N) {
            if (bias) v += bias[n];
            ((float*)out1)[(size_t)m * ldc + n] = v + res[(size_t)m * ldc + n];
          }
        } else if (EPI == 2) {
          if (n < N) {
            v += bias[n];
            v = 0.5f * v * (1.f + erff(v * 0.70710678118654752f));
            ((bf16*)out1)[(size_t)m * ldc + n] = __float2bfloat16(v);
          }
        } else if (EPI == 3) {
          if (n < N) {
            v += bias[n];
            v = (v > 20.f) ? v : log1pf(expf(v));
            ((float*)out1)[(size_t)m * ldc + n] = v;
          }
        } else if (EPI == 4) {
          if (n < 48) {
            ((bf16*)out1)[(size_t)m * 64 + n] = __float2bfloat16(v);
          } else if (n < 80) {
            ((float*)out2)[(size_t)m * 32 + (n - 48)] = v;
          } else if (n < 96) {
            ((bf16*)out1)[(size_t)m * 64 + (n - 32)] = __float2bfloat16(0.f);
          }
        }
      }
    }
  }
}

// ---------------- launch ----------------

extern "C" void kernel_launch(void* const* d_in, const int* in_sizes, int n_in,
                              void* d_out, int out_size, void* d_ws, size_t ws_size,
                              hipStream_t stream) {
  const float* x        = (const float*)d_in[0];
  const float* w_in     = (const float*)d_in[1];
  const float* b_in     = (const float*)d_in[2];
  const float* pe       = (const float*)d_in[3];
  const float* ln1_w    = (const float*)d_in[4];
  const float* ln1_b    = (const float*)d_in[5];
  const float* w_inproj = (const float*)d_in[6];
  const float* conv_w   = (const float*)d_in[7];
  const float* conv_b   = (const float*)d_in[8];
  const float* w_xproj  = (const float*)d_in[9];
  const float* w_dt     = (const float*)d_in[10];
  const float* b_dt     = (const float*)d_in[11];
  const float* A_log    = (const float*)d_in[12];
  const float* Dv       = (const float*)d_in[13];
  const float* w_outproj= (const float*)d_in[14];
  const float* ln2_w    = (const float*)d_in[15];
  const float* ln2_b    = (const float*)d_in[16];
  const float* ff_w1    = (const float*)d_in[17];
  const float* ff_b1    = (const float*)d_in[18];
  const float* ff_w2    = (const float*)d_in[19];
  const float* ff_b2    = (const float*)d_in[20];
  const float* lnf_w    = (const float*)d_in[21];
  const float* lnf_b    = (const float*)d_in[22];
  const float* w_head   = (const float*)d_in[23];
  const float* b_head   = (const float*)d_in[24];
  float* out = (float*)d_out;

  const int M = B_ * S_;  // 2048

  float* wsf = (float*)d_ws;
  float* h    = wsf; wsf += (size_t)M * DM_;
  float* xz   = wsf; wsf += (size_t)M * 2 * DI_;
  float* xc   = wsf; wsf += (size_t)M * DI_;
  float* bc   = wsf; wsf += (size_t)M * 32;
  float* dlt  = wsf; wsf += (size_t)M * DI_;
  float* part = wsf; wsf += 64;
  bf16* wsb = (bf16*)wsf;
  bf16* xln16 = wsb; wsb += (size_t)M * DM_;
  bf16* xcb   = wsb; wsb += (size_t)M * DI_;
  bf16* dtp   = wsb; wsb += (size_t)M * 64;
  bf16* yb16  = wsb; wsb += (size_t)M * DI_;
  bf16* ffh16 = wsb; wsb += (size_t)M * DI_;
  bf16* wip   = wsb; wsb += (size_t)L_ * 2 * DI_ * DM_;
  bf16* wxp   = wsb; wsb += (size_t)L_ * 128 * DI_;
  bf16* wdtp  = wsb; wsb += (size_t)L_ * DI_ * 64;
  bf16* wop   = wsb; wsb += (size_t)L_ * DM_ * DI_;
  bf16* wf1   = wsb; wsb += (size_t)L_ * 2 * DM_ * DM_;
  bf16* wf2   = wsb; wsb += (size_t)L_ * DM_ * 2 * DM_;

  dim3 blk(256);

  {
    int n;
    n = L_ * 2 * DI_ * DM_;  k_cast<<<(n + 255) / 256, blk, 0, stream>>>(w_inproj, wip, n);
    n = L_ * DM_ * DI_;      k_cast<<<(n + 255) / 256, blk, 0, stream>>>(w_outproj, wop, n);
    n = L_ * 2 * DM_ * DM_;  k_cast<<<(n + 255) / 256, blk, 0, stream>>>(ff_w1, wf1, n);
    n = L_ * DM_ * 2 * DM_;  k_cast<<<(n + 255) / 256, blk, 0, stream>>>(ff_w2, wf2, n);
    n = L_ * 128 * DI_;      k_cast_xproj<<<(n + 255) / 256, blk, 0, stream>>>(w_xproj, wxp);
    n = L_ * DI_ * 64;       k_cast_dt<<<(n + 255) / 256, blk, 0, stream>>>(w_dt, wdtp);
  }

  k_embed<<<(B_ * S_ * DM_ + 255) / 256, blk, 0, stream>>>(x, w_in, b_in, pe, h);

  for (int l = 0; l < L_; ++l) {
    k_ln<<<M, blk, 0, stream>>>(h, ln1_w + l * DM_, ln1_b + l * DM_, xln16);

    // xz = xln @ w_inproj^T   (M x 3072, K=768)
    k_gemm_mfma<0><<<dim3(2 * DI_ / 128, M / 128), blk, 0, stream>>>(
        xln16, DM_, wip + (size_t)l * 2 * DI_ * DM_, DM_, nullptr, nullptr,
        xz, nullptr, 2 * DI_, 2 * DI_, DM_);

    k_conv_silu<<<(B_ * S_ * DI_ + 255) / 256, blk, 0, stream>>>(
        xz, conv_w + l * DI_ * KC_, conv_b + l * DI_, xc, xcb);

    // xproj: dtp (bf16, K-padded to 64) + bc (f32)   (M x 96 eff, K=1536)
    k_gemm_mfma<4><<<dim3(1, M / 128), blk, 0, stream>>>(
        xcb, DI_, wxp + (size_t)l * 128 * DI_, DI_, nullptr, nullptr,
        dtp, bc, 0, 96, DI_);

    // delta = softplus(dtp @ wdtp^T + b_dt)   (M x 1536, K=64)
    k_gemm_mfma<3><<<dim3(DI_ / 128, M / 128), blk, 0, stream>>>(
        dtp, 64, wdtp + (size_t)l * DI_ * 64, 64, b_dt + l * DI_, nullptr,
        dlt, nullptr, DI_, DI_, 64);

    // scan + fused gate -> yb16
    k_scan2<<<dim3(DI_ / 16, B_), blk, 0, stream>>>(
        dlt, xc, bc, A_log + (size_t)l * DI_ * DS_, xz, Dv + l * DI_, yb16);

    // h += yb @ w_outproj^T   (M x 768, K=1536)
    k_gemm_mfma<1><<<dim3(DM_ / 128, M / 128), blk, 0, stream>>>(
        yb16, DI_, wop + (size_t)l * DM_ * DI_, DI_, nullptr, h,
        h, nullptr, DM_, DM_, DI_);

    k_ln<<<M, blk, 0, stream>>>(h, ln2_w + l * DM_, ln2_b + l * DM_, xln16);

    // ffh = gelu(xln @ ff_w1^T + b1) -> bf16  (M x 1536, K=768)
    k_gemm_mfma<2><<<dim3(2 * DM_ / 128, M / 128), blk, 0, stream>>>(
        xln16, DM_, wf1 + (size_t)l * 2 * DM_ * DM_, DM_, ff_b1 + l * 2 * DM_, nullptr,
        ffh16, nullptr, 2 * DM_, 2 * DM_, DM_);

    // h += ffh @ ff_w2^T + b2   (M x 768, K=1536)
    k_gemm_mfma<1><<<dim3(DM_ / 128, M / 128), blk, 0, stream>>>(
        ffh16, 2 * DM_, wf2 + (size_t)l * DM_ * 2 * DM_, 2 * DM_, ff_b2 + l * DM_, h,
        h, nullptr, DM_, DM_, DI_);
  }

  k_ln<<<M, blk, 0, stream>>>(h, lnf_w, lnf_b, xln16);
  k_head1<<<dim3(16, B_), blk, 0, stream>>>(xln16, w_head, part);
  k_head2<<<1, 64, 0, stream>>>(part, b_head, out);
}

// Round 4
// 769.795 us; speedup vs baseline: 3.6875x; 1.1236x over previous
//
#include <hip/hip_runtime.h>
#include <hip/hip_bf16.h>
#include <math.h>

#define B_ 4
#define S_ 512
#define DM_ 768
#define L_ 2
#define DI_ 1536
#define DS_ 16
#define KC_ 4
#define DTR_ 48
#define NSEG 8
#define TS 64

typedef __hip_bfloat16 bf16;
typedef __attribute__((ext_vector_type(8))) short short8;
typedef __attribute__((ext_vector_type(4))) float f32x4;

#define GLDS16(g, l) __builtin_amdgcn_global_load_lds( \
    (const __attribute__((address_space(1))) void*)(g), \
    (__attribute__((address_space(3))) void*)(l), 16, 0, 0)

// ---------------- elementwise / small kernels ----------------

__global__ void k_embed(const float* __restrict__ x, const float* __restrict__ w_in,
                        const float* __restrict__ b_in, const float* __restrict__ pe,
                        float* __restrict__ h) {
  int idx = blockIdx.x * 256 + threadIdx.x;
  if (idx >= B_ * S_ * DM_) return;
  int d = idx % DM_;
  int t = idx / DM_;
  int s = t % S_;
  h[idx] = x[t] * w_in[d] + b_in[d] + pe[s * DM_ + d];
}

// LayerNorm over DM; fp32 in, bf16 out
__global__ void k_ln(const float* __restrict__ in, const float* __restrict__ w,
                     const float* __restrict__ b, bf16* __restrict__ out) {
  __shared__ float red1[4], red2[4];
  __shared__ float s_mu, s_rstd;
  int row = blockIdx.x;
  const float* x = in + (size_t)row * DM_;
  float s1 = 0.f, s2 = 0.f;
  for (int i = threadIdx.x; i < DM_; i += 256) { float v = x[i]; s1 += v; s2 += v * v; }
  for (int off = 32; off; off >>= 1) { s1 += __shfl_down(s1, off); s2 += __shfl_down(s2, off); }
  if ((threadIdx.x & 63) == 0) { red1[threadIdx.x >> 6] = s1; red2[threadIdx.x >> 6] = s2; }
  __syncthreads();
  if (threadIdx.x == 0) {
    float t1 = red1[0] + red1[1] + red1[2] + red1[3];
    float t2 = red2[0] + red2[1] + red2[2] + red2[3];
    float mu = t1 * (1.f / DM_);
    float var = t2 * (1.f / DM_) - mu * mu;
    s_mu = mu;
    s_rstd = rsqrtf(var + 1e-5f);
  }
  __syncthreads();
  float mu = s_mu, rstd = s_rstd;
  for (int i = threadIdx.x; i < DM_; i += 256)
    out[(size_t)row * DM_ + i] = __float2bfloat16((x[i] - mu) * rstd * w[i] + b[i]);
}

__global__ void k_cast(const float* __restrict__ src, bf16* __restrict__ dst, int n) {
  int i = blockIdx.x * 256 + threadIdx.x;
  if (i < n) dst[i] = __float2bfloat16(src[i]);
}

// w_xproj (L,80,1536) -> per-layer [128][1536] bf16, rows 80..127 zero
__global__ void k_cast_xproj(const float* __restrict__ src, bf16* __restrict__ dst) {
  int i = blockIdx.x * 256 + threadIdx.x;
  if (i >= 2 * 128 * 1536) return;
  int col = i % 1536;
  int row = (i / 1536) & 127;
  int l = i / (128 * 1536);
  float v = (row < 80) ? src[((size_t)l * 80 + row) * 1536 + col] : 0.f;
  dst[i] = __float2bfloat16(v);
}

// w_dt (L,1536,48) -> [L][1536][64] bf16, cols 48..63 zero
__global__ void k_cast_dt(const float* __restrict__ src, bf16* __restrict__ dst) {
  int i = blockIdx.x * 256 + threadIdx.x;
  if (i >= 2 * 1536 * 64) return;
  int col = i & 63;
  int r = (i >> 6) % 1536;
  int l = i / (1536 * 64);
  float v = (col < 48) ? src[((size_t)l * 1536 + r) * 48 + col] : 0.f;
  dst[i] = __float2bfloat16(v);
}

// depthwise causal conv (K=4) + bias + SiLU; writes fp32 xc and bf16 xcb
__global__ void k_conv_silu(const float* __restrict__ xz, const float* __restrict__ cw,
                            const float* __restrict__ cb, float* __restrict__ xc,
                            bf16* __restrict__ xcb) {
  int idx = blockIdx.x * 256 + threadIdx.x;
  if (idx >= B_ * S_ * DI_) return;
  int d = idx % DI_;
  int t = idx / DI_;
  int s = t % S_;
  int b = t / S_;
  float acc = cb[d];
  const float* base = xz + (size_t)(b * S_) * (2 * DI_) + d;
#pragma unroll
  for (int k = 0; k < KC_; ++k) {
    int ss = s - (KC_ - 1) + k;
    if (ss >= 0) acc = fmaf(base[(size_t)ss * (2 * DI_)], cw[d * KC_ + k], acc);
  }
  float v = acc / (1.f + expf(-acc));
  xc[idx] = v;
  xcb[idx] = __float2bfloat16(v);
}

// ---------------- segmented selective scan ----------------
// Pass A: per (b, seg, 16 d's): local scan with h0=0.
// Writes y_local (+u*D), cumdelta, and segment-final local state hend.
// NOTE: ylocal aliases delta, cumd aliases xc — safe: each block stages its
// exact region into LDS (barrier drains vmcnt) before overwriting it, and
// regions are disjoint across blocks.
__global__ __launch_bounds__(256)
void k_scanA(const float* __restrict__ delta, const float* __restrict__ xc,
             const float* __restrict__ bc, const float* __restrict__ A_log,
             const float* __restrict__ Dv,
             float* __restrict__ ylocal, float* __restrict__ cumd,
             float* __restrict__ hend) {
  __shared__ float sD[TS][16];
  __shared__ float sU[TS][16];
  __shared__ float sBC[TS][32];
  __shared__ float sY[TS][16];
  __shared__ float sCD[TS][16];

  int b = blockIdx.y;
  int seg = blockIdx.z;
  int d0 = blockIdx.x * 16;
  int grp = threadIdx.x >> 4;
  int n = threadIdx.x & 15;
  int d = d0 + grp;
  int s0 = seg * TS;

  {
    int t = threadIdx.x;
    int r = t >> 2;
    int col = (t & 3) * 4;
    size_t go = ((size_t)(b * S_ + s0 + r)) * DI_ + d0 + col;
    GLDS16(delta + go, (char*)&sD[0][0] + t * 16);
    GLDS16(xc + go, (char*)&sU[0][0] + t * 16);
    const char* bptr = (const char*)(bc + ((size_t)(b * S_ + s0)) * 32);
    GLDS16(bptr + t * 16, (char*)&sBC[0][0] + t * 16);
    GLDS16(bptr + 4096 + t * 16, (char*)&sBC[0][0] + 4096 + t * 16);
  }
  __syncthreads();

  float A = -__expf(A_log[d * DS_ + n]);
  float Dd = Dv[d];
  float h = 0.f, cd = 0.f;
#pragma unroll 8
  for (int s = 0; s < TS; ++s) {
    float dl = sD[s][grp];
    float u = sU[s][grp];
    float Bn = sBC[s][n];
    float Cn = sBC[s][16 + n];
    cd += dl;
    h = h * __expf(dl * A) + dl * u * Bn;
    float p = h * Cn;
    p += __shfl_xor(p, 1, 16);
    p += __shfl_xor(p, 2, 16);
    p += __shfl_xor(p, 4, 16);
    p += __shfl_xor(p, 8, 16);
    if (n == 0) { sY[s][grp] = p + u * Dd; sCD[s][grp] = cd; }
  }
  hend[(((size_t)b * NSEG + seg) * DI_ + d) * 16 + n] = h;
  __syncthreads();
  {
    int t = threadIdx.x;
    int r = t >> 2;
    int col = (t & 3) * 4;
    size_t o = ((size_t)(b * S_ + s0 + r)) * DI_ + d0 + col;
    *(float4*)(ylocal + o) = *(float4*)&sY[r][col];
    *(float4*)(cumd + o) = *(float4*)&sCD[r][col];
  }
}

// Pass B: chain segment boundary states (8 sequential steps per (b,d,n))
__global__ void k_scanB(const float* __restrict__ hend, const float* __restrict__ cumd,
                        const float* __restrict__ A_log, float* __restrict__ h0seg) {
  int tid = blockIdx.x * 256 + threadIdx.x;
  if (tid >= B_ * DI_ * 16) return;
  int n = tid & 15;
  int d = (tid >> 4) % DI_;
  int b = tid / (DI_ * 16);
  float A = -__expf(A_log[d * DS_ + n]);
  float h0 = 0.f;
  for (int seg = 0; seg < NSEG; ++seg) {
    size_t idx = (((size_t)b * NSEG + seg) * DI_ + d) * 16 + n;
    h0seg[idx] = h0;
    float cdt = cumd[((size_t)(b * S_ + seg * TS + TS - 1)) * DI_ + d];
    h0 = h0 * __expf(A * cdt) + hend[idx];
  }
}

// Pass C: y = (y_local + sum_n C[n]*exp(A_n*cumd)*h0seg[n]) * silu(z) -> bf16
__global__ __launch_bounds__(256)
void k_scanC(const float* __restrict__ ylocal, const float* __restrict__ cumd,
             const float* __restrict__ bc, const float* __restrict__ A_log,
             const float* __restrict__ h0seg, const float* __restrict__ xz,
             bf16* __restrict__ yb16) {
  int d = blockIdx.x * 256 + threadIdx.x;
  int t = blockIdx.y;
  int b = blockIdx.z;
  int seg = t / TS;
  size_t o = ((size_t)(b * S_ + t)) * DI_ + d;
  float y = ylocal[o];
  if (seg) {
    float cd = cumd[o];
    const float* Cp = bc + ((size_t)(b * S_ + t)) * 32 + 16;
    const float* Ap = A_log + d * DS_;
    const float* Hp = h0seg + (((size_t)b * NSEG + seg) * DI_ + d) * 16;
#pragma unroll
    for (int n = 0; n < 16; ++n)
      y += Cp[n] * __expf(-__expf(Ap[n]) * cd) * Hp[n];
  }
  float z = xz[((size_t)(b * S_ + t)) * (2 * DI_) + DI_ + d];
  float sig = 1.f / (1.f + __expf(-z));
  yb16[o] = __float2bfloat16(y * (z * sig));
}

// head stage 1: block (j,b) reduces rows s in [j*32, j*32+32)
__global__ void k_head1(const bf16* __restrict__ hf, const float* __restrict__ wh,
                        float* __restrict__ partial) {
  __shared__ float red[4];
  int b = blockIdx.y, j = blockIdx.x;
  const bf16* base = hf + ((size_t)b * S_ + j * 32) * DM_;
  float acc = 0.f;
  for (int i = threadIdx.x; i < 32 * DM_; i += 256) {
    int dd = i - (i / DM_) * DM_;
    acc += __bfloat162float(base[i]) * wh[dd];
  }
  for (int off = 32; off; off >>= 1) acc += __shfl_down(acc, off);
  if ((threadIdx.x & 63) == 0) red[threadIdx.x >> 6] = acc;
  __syncthreads();
  if (threadIdx.x == 0)
    partial[b * 16 + j] = red[0] + red[1] + red[2] + red[3];
}

__global__ void k_head2(const float* __restrict__ partial, const float* __restrict__ bh,
                        float* __restrict__ out) {
  int b = threadIdx.x;
  if (b < B_) {
    float acc = 0.f;
    for (int j = 0; j < 16; ++j) acc += partial[b * 16 + j];
    out[b] = acc * (1.f / S_) + bh[0];
  }
}

// ---------------- MFMA GEMM ----------------
template <int EPI>
__global__ __launch_bounds__(256)
void k_gemm_mfma(const bf16* __restrict__ A, int lda,
                 const bf16* __restrict__ W, int ldw,
                 const float* __restrict__ bias,
                 const float* __restrict__ res,
                 void* __restrict__ out1, void* __restrict__ out2,
                 int ldc, int N, int Kdim) {
  __shared__ short As[128 * 32];
  __shared__ short Bs[128 * 32];
  int m0 = blockIdx.y * 128;
  int n0 = blockIdx.x * 128;
  int wid = threadIdx.x >> 6;
  int lane = threadIdx.x & 63;
  int wm = wid >> 1, wn = wid & 1;
  int lr = lane & 15;
  int kb = (lane >> 4) * 8;

  f32x4 acc[4][4];
#pragma unroll
  for (int i = 0; i < 4; ++i)
#pragma unroll
    for (int j = 0; j < 4; ++j) {
      acc[i][j][0] = 0.f; acc[i][j][1] = 0.f; acc[i][j][2] = 0.f; acc[i][j][3] = 0.f;
    }

  for (int k0 = 0; k0 < Kdim; k0 += 32) {
#pragma unroll
    for (int c0 = 0; c0 < 2; ++c0) {
      int c = c0 * 256 + threadIdx.x;
      GLDS16(A + (size_t)(m0 + (c >> 2)) * lda + k0 + (c & 3) * 8, (char*)As + c * 16);
    }
#pragma unroll
    for (int c0 = 0; c0 < 2; ++c0) {
      int c = c0 * 256 + threadIdx.x;
      GLDS16(W + (size_t)(n0 + (c >> 2)) * ldw + k0 + (c & 3) * 8, (char*)Bs + c * 16);
    }
    __syncthreads();

    short8 a[4], b[4];
#pragma unroll
    for (int f = 0; f < 4; ++f) {
      a[f] = *(const short8*)&As[(wm * 64 + f * 16 + lr) * 32 + kb];
      b[f] = *(const short8*)&Bs[(wn * 64 + f * 16 + lr) * 32 + kb];
    }
#pragma unroll
    for (int i = 0; i < 4; ++i)
#pragma unroll
      for (int j = 0; j < 4; ++j)
        acc[i][j] = __builtin_amdgcn_mfma_f32_16x16x32_bf16(a[i], b[j], acc[i][j], 0, 0, 0);
    __syncthreads();
  }

#pragma unroll
  for (int i = 0; i < 4; ++i) {
#pragma unroll
    for (int j = 0; j < 4; ++j) {
      int n = n0 + wn * 64 + j * 16 + (lane & 15);
#pragma unroll
      for (int q = 0; q < 4; ++q) {
        int m = m0 + wm * 64 + i * 16 + (lane >> 4) * 4 + q;
        float v = acc[i][j][q];
        if (EPI == 0) {
          if (n < N) ((float*)out1)[(size_t)m * ldc + n] = v;
        } else if (EPI == 1) {
          if (n < N) {
            if (bias) v += bias[n];
            ((float*)out1)[(size_t)m * ldc + n] = v + res[(size_t)m * ldc + n];
          }
        } else if (EPI == 2) {
          if (n < N) {
            v += bias[n];
            v = 0.5f * v * (1.f + erff(v * 0.70710678118654752f));
            ((bf16*)out1)[(size_t)m * ldc + n] = __float2bfloat16(v);
          }
        } else if (EPI == 3) {
          if (n < N) {
            v += bias[n];
            v = (v > 20.f) ? v : log1pf(expf(v));
            ((float*)out1)[(size_t)m * ldc + n] = v;
          }
        } else if (EPI == 4) {
          if (n < 48) {
            ((bf16*)out1)[(size_t)m * 64 + n] = __float2bfloat16(v);
          } else if (n < 80) {
            ((float*)out2)[(size_t)m * 32 + (n - 48)] = v;
          } else if (n < 96) {
            ((bf16*)out1)[(size_t)m * 64 + (n - 32)] = __float2bfloat16(0.f);
          }
        }
      }
    }
  }
}

// ---------------- launch ----------------

extern "C" void kernel_launch(void* const* d_in, const int* in_sizes, int n_in,
                              void* d_out, int out_size, void* d_ws, size_t ws_size,
                              hipStream_t stream) {
  const float* x        = (const float*)d_in[0];
  const float* w_in     = (const float*)d_in[1];
  const float* b_in     = (const float*)d_in[2];
  const float* pe       = (const float*)d_in[3];
  const float* ln1_w    = (const float*)d_in[4];
  const float* ln1_b    = (const float*)d_in[5];
  const float* w_inproj = (const float*)d_in[6];
  const float* conv_w   = (const float*)d_in[7];
  const float* conv_b   = (const float*)d_in[8];
  const float* w_xproj  = (const float*)d_in[9];
  const float* w_dt     = (const float*)d_in[10];
  const float* b_dt     = (const float*)d_in[11];
  const float* A_log    = (const float*)d_in[12];
  const float* Dv       = (const float*)d_in[13];
  const float* w_outproj= (const float*)d_in[14];
  const float* ln2_w    = (const float*)d_in[15];
  const float* ln2_b    = (const float*)d_in[16];
  const float* ff_w1    = (const float*)d_in[17];
  const float* ff_b1    = (const float*)d_in[18];
  const float* ff_w2    = (const float*)d_in[19];
  const float* ff_b2    = (const float*)d_in[20];
  const float* lnf_w    = (const float*)d_in[21];
  const float* lnf_b    = (const float*)d_in[22];
  const float* w_head   = (const float*)d_in[23];
  const float* b_head   = (const float*)d_in[24];
  float* out = (float*)d_out;

  const int M = B_ * S_;  // 2048

  float* wsf = (float*)d_ws;
  float* h    = wsf; wsf += (size_t)M * DM_;
  float* xz   = wsf; wsf += (size_t)M * 2 * DI_;
  float* xc   = wsf; wsf += (size_t)M * DI_;
  float* bc   = wsf; wsf += (size_t)M * 32;
  float* dlt  = wsf; wsf += (size_t)M * DI_;
  float* hend = wsf; wsf += (size_t)B_ * NSEG * DI_ * 16;
  float* h0sg = wsf; wsf += (size_t)B_ * NSEG * DI_ * 16;
  float* part = wsf; wsf += 64;
  bf16* wsb = (bf16*)wsf;
  bf16* xln16 = wsb; wsb += (size_t)M * DM_;
  bf16* xcb   = wsb; wsb += (size_t)M * DI_;
  bf16* dtp   = wsb; wsb += (size_t)M * 64;
  bf16* yb16  = wsb; wsb += (size_t)M * DI_;
  bf16* ffh16 = wsb; wsb += (size_t)M * DI_;
  bf16* wip   = wsb; wsb += (size_t)L_ * 2 * DI_ * DM_;
  bf16* wxp   = wsb; wsb += (size_t)L_ * 128 * DI_;
  bf16* wdtp  = wsb; wsb += (size_t)L_ * DI_ * 64;
  bf16* wop   = wsb; wsb += (size_t)L_ * DM_ * DI_;
  bf16* wf1   = wsb; wsb += (size_t)L_ * 2 * DM_ * DM_;
  bf16* wf2   = wsb; wsb += (size_t)L_ * DM_ * 2 * DM_;

  // scan pass A outputs alias their own staged inputs (see k_scanA note)
  float* ylocal = dlt;
  float* cumd   = xc;

  dim3 blk(256);

  {
    int n;
    n = L_ * 2 * DI_ * DM_;  k_cast<<<(n + 255) / 256, blk, 0, stream>>>(w_inproj, wip, n);
    n = L_ * DM_ * DI_;      k_cast<<<(n + 255) / 256, blk, 0, stream>>>(w_outproj, wop, n);
    n = L_ * 2 * DM_ * DM_;  k_cast<<<(n + 255) / 256, blk, 0, stream>>>(ff_w1, wf1, n);
    n = L_ * DM_ * 2 * DM_;  k_cast<<<(n + 255) / 256, blk, 0, stream>>>(ff_w2, wf2, n);
    n = L_ * 128 * DI_;      k_cast_xproj<<<(n + 255) / 256, blk, 0, stream>>>(w_xproj, wxp);
    n = L_ * DI_ * 64;       k_cast_dt<<<(n + 255) / 256, blk, 0, stream>>>(w_dt, wdtp);
  }

  k_embed<<<(B_ * S_ * DM_ + 255) / 256, blk, 0, stream>>>(x, w_in, b_in, pe, h);

  for (int l = 0; l < L_; ++l) {
    k_ln<<<M, blk, 0, stream>>>(h, ln1_w + l * DM_, ln1_b + l * DM_, xln16);

    // xz = xln @ w_inproj^T   (M x 3072, K=768)
    k_gemm_mfma<0><<<dim3(2 * DI_ / 128, M / 128), blk, 0, stream>>>(
        xln16, DM_, wip + (size_t)l * 2 * DI_ * DM_, DM_, nullptr, nullptr,
        xz, nullptr, 2 * DI_, 2 * DI_, DM_);

    k_conv_silu<<<(B_ * S_ * DI_ + 255) / 256, blk, 0, stream>>>(
        xz, conv_w + l * DI_ * KC_, conv_b + l * DI_, xc, xcb);

    // xproj: dtp (bf16, K-padded to 64) + bc (f32)   (M x 96 eff, K=1536)
    k_gemm_mfma<4><<<dim3(1, M / 128), blk, 0, stream>>>(
        xcb, DI_, wxp + (size_t)l * 128 * DI_, DI_, nullptr, nullptr,
        dtp, bc, 0, 96, DI_);

    // delta = softplus(dtp @ wdtp^T + b_dt)   (M x 1536, K=64)
    k_gemm_mfma<3><<<dim3(DI_ / 128, M / 128), blk, 0, stream>>>(
        dtp, 64, wdtp + (size_t)l * DI_ * 64, 64, b_dt + l * DI_, nullptr,
        dlt, nullptr, DI_, DI_, 64);

    // segmented scan: A (parallel local scans), B (boundary chain), C (correct+gate)
    k_scanA<<<dim3(DI_ / 16, B_, NSEG), blk, 0, stream>>>(
        dlt, xc, bc, A_log + (size_t)l * DI_ * DS_, Dv + l * DI_,
        ylocal, cumd, hend);
    k_scanB<<<(B_ * DI_ * 16 + 255) / 256, blk, 0, stream>>>(
        hend, cumd, A_log + (size_t)l * DI_ * DS_, h0sg);
    k_scanC<<<dim3(DI_ / 256, S_, B_), blk, 0, stream>>>(
        ylocal, cumd, bc, A_log + (size_t)l * DI_ * DS_, h0sg, xz, yb16);

    // h += yb @ w_outproj^T   (M x 768, K=1536)
    k_gemm_mfma<1><<<dim3(DM_ / 128, M / 128), blk, 0, stream>>>(
        yb16, DI_, wop + (size_t)l * DM_ * DI_, DI_, nullptr, h,
        h, nullptr, DM_, DM_, DI_);

    k_ln<<<M, blk, 0, stream>>>(h, ln2_w + l * DM_, ln2_b + l * DM_, xln16);

    // ffh = gelu(xln @ ff_w1^T + b1) -> bf16  (M x 1536, K=768)
    k_gemm_mfma<2><<<dim3(2 * DM_ / 128, M / 128), blk, 0, stream>>>(
        xln16, DM_, wf1 + (size_t)l * 2 * DM_ * DM_, DM_, ff_b1 + l * 2 * DM_, nullptr,
        ffh16, nullptr, 2 * DM_, 2 * DM_, DM_);

    // h += ffh @ ff_w2^T + b2   (M x 768, K=1536)
    k_gemm_mfma<1><<<dim3(DM_ / 128, M / 128), blk, 0, stream>>>(
        ffh16, 2 * DM_, wf2 + (size_t)l * DM_ * 2 * DM_, 2 * DM_, ff_b2 + l * DM_, h,
        h, nullptr, DM_, DM_, DI_);
  }

  k_ln<<<M, blk, 0, stream>>>(h, lnf_w, lnf_b, xln16);
  k_head1<<<dim3(16, B_), blk, 0, stream>>>(xln16, w_head, part);
  k_head2<<<1, 64, 0, stream>>>(part, b_head, out);
}

// Round 5
// 744.062 us; speedup vs baseline: 3.8150x; 1.0346x over previous
//
#include <hip/hip_runtime.h>
#include <hip/hip_bf16.h>
#include <math.h>

#define B_ 4
#define S_ 512
#define DM_ 768
#define L_ 2
#define DI_ 1536
#define DS_ 16
#define KC_ 4
#define DTR_ 48
#define NSEG 8
#define TS 64

typedef __hip_bfloat16 bf16;
typedef __attribute__((ext_vector_type(8))) short short8;
typedef __attribute__((ext_vector_type(4))) float f32x4;

#define GLDS16(g, l) __builtin_amdgcn_global_load_lds( \
    (const __attribute__((address_space(1))) void*)(g), \
    (__attribute__((address_space(3))) void*)(l), 16, 0, 0)

// ---------------- elementwise / small kernels ----------------

__global__ void k_embed(const float* __restrict__ x, const float* __restrict__ w_in,
                        const float* __restrict__ b_in, const float* __restrict__ pe,
                        float* __restrict__ h) {
  int idx = blockIdx.x * 256 + threadIdx.x;
  if (idx >= B_ * S_ * DM_) return;
  int d = idx % DM_;
  int t = idx / DM_;
  int s = t % S_;
  h[idx] = x[t] * w_in[d] + b_in[d] + pe[s * DM_ + d];
}

// LayerNorm over DM; fp32 in, bf16 out
__global__ void k_ln(const float* __restrict__ in, const float* __restrict__ w,
                     const float* __restrict__ b, bf16* __restrict__ out) {
  __shared__ float red1[4], red2[4];
  __shared__ float s_mu, s_rstd;
  int row = blockIdx.x;
  const float* x = in + (size_t)row * DM_;
  float s1 = 0.f, s2 = 0.f;
  for (int i = threadIdx.x; i < DM_; i += 256) { float v = x[i]; s1 += v; s2 += v * v; }
  for (int off = 32; off; off >>= 1) { s1 += __shfl_down(s1, off); s2 += __shfl_down(s2, off); }
  if ((threadIdx.x & 63) == 0) { red1[threadIdx.x >> 6] = s1; red2[threadIdx.x >> 6] = s2; }
  __syncthreads();
  if (threadIdx.x == 0) {
    float t1 = red1[0] + red1[1] + red1[2] + red1[3];
    float t2 = red2[0] + red2[1] + red2[2] + red2[3];
    float mu = t1 * (1.f / DM_);
    float var = t2 * (1.f / DM_) - mu * mu;
    s_mu = mu;
    s_rstd = rsqrtf(var + 1e-5f);
  }
  __syncthreads();
  float mu = s_mu, rstd = s_rstd;
  for (int i = threadIdx.x; i < DM_; i += 256)
    out[(size_t)row * DM_ + i] = __float2bfloat16((x[i] - mu) * rstd * w[i] + b[i]);
}

__global__ void k_cast(const float* __restrict__ src, bf16* __restrict__ dst, int n) {
  int i = blockIdx.x * 256 + threadIdx.x;
  if (i < n) dst[i] = __float2bfloat16(src[i]);
}

// w_xproj (L,80,1536) -> per-layer [128][1536] bf16, rows 80..127 zero
__global__ void k_cast_xproj(const float* __restrict__ src, bf16* __restrict__ dst) {
  int i = blockIdx.x * 256 + threadIdx.x;
  if (i >= 2 * 128 * 1536) return;
  int col = i % 1536;
  int row = (i / 1536) & 127;
  int l = i / (128 * 1536);
  float v = (row < 80) ? src[((size_t)l * 80 + row) * 1536 + col] : 0.f;
  dst[i] = __float2bfloat16(v);
}

// w_dt (L,1536,48) -> [L][1536][64] bf16, cols 48..63 zero
__global__ void k_cast_dt(const float* __restrict__ src, bf16* __restrict__ dst) {
  int i = blockIdx.x * 256 + threadIdx.x;
  if (i >= 2 * 1536 * 64) return;
  int col = i & 63;
  int r = (i >> 6) % 1536;
  int l = i / (1536 * 64);
  float v = (col < 48) ? src[((size_t)l * 1536 + r) * 48 + col] : 0.f;
  dst[i] = __float2bfloat16(v);
}

// depthwise causal conv (K=4) + bias + SiLU; writes fp32 xc and bf16 xcb
__global__ void k_conv_silu(const float* __restrict__ xz, const float* __restrict__ cw,
                            const float* __restrict__ cb, float* __restrict__ xc,
                            bf16* __restrict__ xcb) {
  int idx = blockIdx.x * 256 + threadIdx.x;
  if (idx >= B_ * S_ * DI_) return;
  int d = idx % DI_;
  int t = idx / DI_;
  int s = t % S_;
  int b = t / S_;
  float acc = cb[d];
  const float* base = xz + (size_t)(b * S_) * (2 * DI_) + d;
#pragma unroll
  for (int k = 0; k < KC_; ++k) {
    int ss = s - (KC_ - 1) + k;
    if (ss >= 0) acc = fmaf(base[(size_t)ss * (2 * DI_)], cw[d * KC_ + k], acc);
  }
  float v = acc / (1.f + expf(-acc));
  xc[idx] = v;
  xcb[idx] = __float2bfloat16(v);
}

// ---------------- segmented selective scan ----------------
// Pass A v2: one thread per d; 16 states in VGPRs; no LDS, no shuffles.
// delta/xc loads coalesced (lane = consecutive d); B/C loads wave-uniform -> SMEM.
// ylocal aliases delta, cumd aliases xc: each thread reads [s,d] before writing
// the same [s,d] (same-thread program order -> safe).
__global__ __launch_bounds__(256)
void k_scanA(const float* __restrict__ delta, const float* __restrict__ xc,
             const float* __restrict__ bc, const float* __restrict__ A_log,
             const float* __restrict__ Dv,
             float* __restrict__ ylocal, float* __restrict__ cumd,
             float* __restrict__ hend) {
  int b = blockIdx.y;
  int seg = blockIdx.z;
  int d = blockIdx.x * 256 + threadIdx.x;
  int s0 = seg * TS;

  float A[16], hst[16];
#pragma unroll
  for (int n = 0; n < 16; ++n) {
    A[n] = -__expf(A_log[d * DS_ + n]);
    hst[n] = 0.f;
  }
  float Dd = Dv[d];
  float cd = 0.f;

  const float* dp = delta + ((size_t)(b * S_ + s0)) * DI_ + d;
  const float* up = xc + ((size_t)(b * S_ + s0)) * DI_ + d;
  const float* bp = bc + ((size_t)(b * S_ + s0)) * 32;
  float* yp = ylocal + ((size_t)(b * S_ + s0)) * DI_ + d;
  float* cp = cumd + ((size_t)(b * S_ + s0)) * DI_ + d;

  float dl_next = dp[0];
  float u_next = up[0];
#pragma unroll 4
  for (int s = 0; s < TS; ++s) {
    float dl = dl_next, u = u_next;
    if (s + 1 < TS) {
      dl_next = dp[(size_t)(s + 1) * DI_];
      u_next = up[(size_t)(s + 1) * DI_];
    }
    cd += dl;
    float dlu = dl * u;
    float y = 0.f;
#pragma unroll
    for (int n = 0; n < 16; ++n) {
      float e = __expf(dl * A[n]);
      hst[n] = fmaf(hst[n], e, dlu * bp[s * 32 + n]);
      y = fmaf(hst[n], bp[s * 32 + 16 + n], y);
    }
    yp[(size_t)s * DI_] = fmaf(u, Dd, y);
    cp[(size_t)s * DI_] = cd;
  }
  float* hp = hend + (((size_t)b * NSEG + seg) * DI_ + d) * 16;
#pragma unroll
  for (int n = 0; n < 16; ++n) hp[n] = hst[n];
}

// Pass B: chain segment boundary states (8 sequential steps per (b,d,n))
__global__ void k_scanB(const float* __restrict__ hend, const float* __restrict__ cumd,
                        const float* __restrict__ A_log, float* __restrict__ h0seg) {
  int tid = blockIdx.x * 256 + threadIdx.x;
  if (tid >= B_ * DI_ * 16) return;
  int n = tid & 15;
  int d = (tid >> 4) % DI_;
  int b = tid / (DI_ * 16);
  float A = -__expf(A_log[d * DS_ + n]);
  float h0 = 0.f;
  for (int seg = 0; seg < NSEG; ++seg) {
    size_t idx = (((size_t)b * NSEG + seg) * DI_ + d) * 16 + n;
    h0seg[idx] = h0;
    float cdt = cumd[((size_t)(b * S_ + seg * TS + TS - 1)) * DI_ + d];
    h0 = h0 * __expf(A * cdt) + hend[idx];
  }
}

// Pass C: y = (y_local + sum_n C[n]*exp(A_n*cumd)*h0seg[n]) * silu(z) -> bf16
__global__ __launch_bounds__(256)
void k_scanC(const float* __restrict__ ylocal, const float* __restrict__ cumd,
             const float* __restrict__ bc, const float* __restrict__ A_log,
             const float* __restrict__ h0seg, const float* __restrict__ xz,
             bf16* __restrict__ yb16) {
  int d = blockIdx.x * 256 + threadIdx.x;
  int t = blockIdx.y;
  int b = blockIdx.z;
  int seg = t / TS;
  size_t o = ((size_t)(b * S_ + t)) * DI_ + d;
  float y = ylocal[o];
  if (seg) {
    float cd = cumd[o];
    const float* Cp = bc + ((size_t)(b * S_ + t)) * 32 + 16;
    const float* Ap = A_log + d * DS_;
    const float* Hp = h0seg + (((size_t)b * NSEG + seg) * DI_ + d) * 16;
#pragma unroll
    for (int n = 0; n < 16; ++n)
      y += Cp[n] * __expf(-__expf(Ap[n]) * cd) * Hp[n];
  }
  float z = xz[((size_t)(b * S_ + t)) * (2 * DI_) + DI_ + d];
  float sig = 1.f / (1.f + __expf(-z));
  yb16[o] = __float2bfloat16(y * (z * sig));
}

// head stage 1: block (j,b) reduces rows s in [j*32, j*32+32)
__global__ void k_head1(const bf16* __restrict__ hf, const float* __restrict__ wh,
                        float* __restrict__ partial) {
  __shared__ float red[4];
  int b = blockIdx.y, j = blockIdx.x;
  const bf16* base = hf + ((size_t)b * S_ + j * 32) * DM_;
  float acc = 0.f;
  for (int i = threadIdx.x; i < 32 * DM_; i += 256) {
    int dd = i - (i / DM_) * DM_;
    acc += __bfloat162float(base[i]) * wh[dd];
  }
  for (int off = 32; off; off >>= 1) acc += __shfl_down(acc, off);
  if ((threadIdx.x & 63) == 0) red[threadIdx.x >> 6] = acc;
  __syncthreads();
  if (threadIdx.x == 0)
    partial[b * 16 + j] = red[0] + red[1] + red[2] + red[3];
}

__global__ void k_head2(const float* __restrict__ partial, const float* __restrict__ bh,
                        float* __restrict__ out) {
  int b = threadIdx.x;
  if (b < B_) {
    float acc = 0.f;
    for (int j = 0; j < 16; ++j) acc += partial[b * 16 + j];
    out[b] = acc * (1.f / S_) + bh[0];
  }
}

// ---------------- MFMA GEMM ----------------
template <int EPI>
__global__ __launch_bounds__(256)
void k_gemm_mfma(const bf16* __restrict__ A, int lda,
                 const bf16* __restrict__ W, int ldw,
                 const float* __restrict__ bias,
                 const float* __restrict__ res,
                 void* __restrict__ out1, void* __restrict__ out2,
                 int ldc, int N, int Kdim) {
  __shared__ short As[128 * 32];
  __shared__ short Bs[128 * 32];
  int m0 = blockIdx.y * 128;
  int n0 = blockIdx.x * 128;
  int wid = threadIdx.x >> 6;
  int lane = threadIdx.x & 63;
  int wm = wid >> 1, wn = wid & 1;
  int lr = lane & 15;
  int kb = (lane >> 4) * 8;

  f32x4 acc[4][4];
#pragma unroll
  for (int i = 0; i < 4; ++i)
#pragma unroll
    for (int j = 0; j < 4; ++j) {
      acc[i][j][0] = 0.f; acc[i][j][1] = 0.f; acc[i][j][2] = 0.f; acc[i][j][3] = 0.f;
    }

  for (int k0 = 0; k0 < Kdim; k0 += 32) {
#pragma unroll
    for (int c0 = 0; c0 < 2; ++c0) {
      int c = c0 * 256 + threadIdx.x;
      GLDS16(A + (size_t)(m0 + (c >> 2)) * lda + k0 + (c & 3) * 8, (char*)As + c * 16);
    }
#pragma unroll
    for (int c0 = 0; c0 < 2; ++c0) {
      int c = c0 * 256 + threadIdx.x;
      GLDS16(W + (size_t)(n0 + (c >> 2)) * ldw + k0 + (c & 3) * 8, (char*)Bs + c * 16);
    }
    __syncthreads();

    short8 a[4], b[4];
#pragma unroll
    for (int f = 0; f < 4; ++f) {
      a[f] = *(const short8*)&As[(wm * 64 + f * 16 + lr) * 32 + kb];
      b[f] = *(const short8*)&Bs[(wn * 64 + f * 16 + lr) * 32 + kb];
    }
#pragma unroll
    for (int i = 0; i < 4; ++i)
#pragma unroll
      for (int j = 0; j < 4; ++j)
        acc[i][j] = __builtin_amdgcn_mfma_f32_16x16x32_bf16(a[i], b[j], acc[i][j], 0, 0, 0);
    __syncthreads();
  }

#pragma unroll
  for (int i = 0; i < 4; ++i) {
#pragma unroll
    for (int j = 0; j < 4; ++j) {
      int n = n0 + wn * 64 + j * 16 + (lane & 15);
#pragma unroll
      for (int q = 0; q < 4; ++q) {
        int m = m0 + wm * 64 + i * 16 + (lane >> 4) * 4 + q;
        float v = acc[i][j][q];
        if (EPI == 0) {
          if (n < N) ((float*)out1)[(size_t)m * ldc + n] = v;
        } else if (EPI == 1) {
          if (n < N) {
            if (bias) v += bias[n];
            ((float*)out1)[(size_t)m * ldc + n] = v + res[(size_t)m * ldc + n];
          }
        } else if (EPI == 2) {
          if (n < N) {
            v += bias[n];
            v = 0.5f * v * (1.f + erff(v * 0.70710678118654752f));
            ((bf16*)out1)[(size_t)m * ldc + n] = __float2bfloat16(v);
          }
        } else if (EPI == 3) {
          if (n < N) {
            v += bias[n];
            v = (v > 20.f) ? v : log1pf(expf(v));
            ((float*)out1)[(size_t)m * ldc + n] = v;
          }
        } else if (EPI == 4) {
          if (n < 48) {
            ((bf16*)out1)[(size_t)m * 64 + n] = __float2bfloat16(v);
          } else if (n < 80) {
            ((float*)out2)[(size_t)m * 32 + (n - 48)] = v;
          } else if (n < 96) {
            ((bf16*)out1)[(size_t)m * 64 + (n - 32)] = __float2bfloat16(0.f);
          }
        }
      }
    }
  }
}

// ---------------- launch ----------------

extern "C" void kernel_launch(void* const* d_in, const int* in_sizes, int n_in,
                              void* d_out, int out_size, void* d_ws, size_t ws_size,
                              hipStream_t stream) {
  const float* x        = (const float*)d_in[0];
  const float* w_in     = (const float*)d_in[1];
  const float* b_in     = (const float*)d_in[2];
  const float* pe       = (const float*)d_in[3];
  const float* ln1_w    = (const float*)d_in[4];
  const float* ln1_b    = (const float*)d_in[5];
  const float* w_inproj = (const float*)d_in[6];
  const float* conv_w   = (const float*)d_in[7];
  const float* conv_b   = (const float*)d_in[8];
  const float* w_xproj  = (const float*)d_in[9];
  const float* w_dt     = (const float*)d_in[10];
  const float* b_dt     = (const float*)d_in[11];
  const float* A_log    = (const float*)d_in[12];
  const float* Dv       = (const float*)d_in[13];
  const float* w_outproj= (const float*)d_in[14];
  const float* ln2_w    = (const float*)d_in[15];
  const float* ln2_b    = (const float*)d_in[16];
  const float* ff_w1    = (const float*)d_in[17];
  const float* ff_b1    = (const float*)d_in[18];
  const float* ff_w2    = (const float*)d_in[19];
  const float* ff_b2    = (const float*)d_in[20];
  const float* lnf_w    = (const float*)d_in[21];
  const float* lnf_b    = (const float*)d_in[22];
  const float* w_head   = (const float*)d_in[23];
  const float* b_head   = (const float*)d_in[24];
  float* out = (float*)d_out;

  const int M = B_ * S_;  // 2048

  float* wsf = (float*)d_ws;
  float* h    = wsf; wsf += (size_t)M * DM_;
  float* xz   = wsf; wsf += (size_t)M * 2 * DI_;
  float* xc   = wsf; wsf += (size_t)M * DI_;
  float* bc   = wsf; wsf += (size_t)M * 32;
  float* dlt  = wsf; wsf += (size_t)M * DI_;
  float* hend = wsf; wsf += (size_t)B_ * NSEG * DI_ * 16;
  float* h0sg = wsf; wsf += (size_t)B_ * NSEG * DI_ * 16;
  float* part = wsf; wsf += 64;
  bf16* wsb = (bf16*)wsf;
  bf16* xln16 = wsb; wsb += (size_t)M * DM_;
  bf16* xcb   = wsb; wsb += (size_t)M * DI_;
  bf16* dtp   = wsb; wsb += (size_t)M * 64;
  bf16* yb16  = wsb; wsb += (size_t)M * DI_;
  bf16* ffh16 = wsb; wsb += (size_t)M * DI_;
  bf16* wip   = wsb; wsb += (size_t)L_ * 2 * DI_ * DM_;
  bf16* wxp   = wsb; wsb += (size_t)L_ * 128 * DI_;
  bf16* wdtp  = wsb; wsb += (size_t)L_ * DI_ * 64;
  bf16* wop   = wsb; wsb += (size_t)L_ * DM_ * DI_;
  bf16* wf1   = wsb; wsb += (size_t)L_ * 2 * DM_ * DM_;
  bf16* wf2   = wsb; wsb += (size_t)L_ * DM_ * 2 * DM_;

  // scan pass A outputs alias their own per-thread-read inputs (see k_scanA note)
  float* ylocal = dlt;
  float* cumd   = xc;

  dim3 blk(256);

  {
    int n;
    n = L_ * 2 * DI_ * DM_;  k_cast<<<(n + 255) / 256, blk, 0, stream>>>(w_inproj, wip, n);
    n = L_ * DM_ * DI_;      k_cast<<<(n + 255) / 256, blk, 0, stream>>>(w_outproj, wop, n);
    n = L_ * 2 * DM_ * DM_;  k_cast<<<(n + 255) / 256, blk, 0, stream>>>(ff_w1, wf1, n);
    n = L_ * DM_ * 2 * DM_;  k_cast<<<(n + 255) / 256, blk, 0, stream>>>(ff_w2, wf2, n);
    n = L_ * 128 * DI_;      k_cast_xproj<<<(n + 255) / 256, blk, 0, stream>>>(w_xproj, wxp);
    n = L_ * DI_ * 64;       k_cast_dt<<<(n + 255) / 256, blk, 0, stream>>>(w_dt, wdtp);
  }

  k_embed<<<(B_ * S_ * DM_ + 255) / 256, blk, 0, stream>>>(x, w_in, b_in, pe, h);

  for (int l = 0; l < L_; ++l) {
    k_ln<<<M, blk, 0, stream>>>(h, ln1_w + l * DM_, ln1_b + l * DM_, xln16);

    // xz = xln @ w_inproj^T   (M x 3072, K=768)
    k_gemm_mfma<0><<<dim3(2 * DI_ / 128, M / 128), blk, 0, stream>>>(
        xln16, DM_, wip + (size_t)l * 2 * DI_ * DM_, DM_, nullptr, nullptr,
        xz, nullptr, 2 * DI_, 2 * DI_, DM_);

    k_conv_silu<<<(B_ * S_ * DI_ + 255) / 256, blk, 0, stream>>>(
        xz, conv_w + l * DI_ * KC_, conv_b + l * DI_, xc, xcb);

    // xproj: dtp (bf16, K-padded to 64) + bc (f32)   (M x 96 eff, K=1536)
    k_gemm_mfma<4><<<dim3(1, M / 128), blk, 0, stream>>>(
        xcb, DI_, wxp + (size_t)l * 128 * DI_, DI_, nullptr, nullptr,
        dtp, bc, 0, 96, DI_);

    // delta = softplus(dtp @ wdtp^T + b_dt)   (M x 1536, K=64)
    k_gemm_mfma<3><<<dim3(DI_ / 128, M / 128), blk, 0, stream>>>(
        dtp, 64, wdtp + (size_t)l * DI_ * 64, 64, b_dt + l * DI_, nullptr,
        dlt, nullptr, DI_, DI_, 64);

    // segmented scan: A (parallel local scans), B (boundary chain), C (correct+gate)
    k_scanA<<<dim3(DI_ / 256, B_, NSEG), blk, 0, stream>>>(
        dlt, xc, bc, A_log + (size_t)l * DI_ * DS_, Dv + l * DI_,
        ylocal, cumd, hend);
    k_scanB<<<(B_ * DI_ * 16 + 255) / 256, blk, 0, stream>>>(
        hend, cumd, A_log + (size_t)l * DI_ * DS_, h0sg);
    k_scanC<<<dim3(DI_ / 256, S_, B_), blk, 0, stream>>>(
        ylocal, cumd, bc, A_log + (size_t)l * DI_ * DS_, h0sg, xz, yb16);

    // h += yb @ w_outproj^T   (M x 768, K=1536)
    k_gemm_mfma<1><<<dim3(DM_ / 128, M / 128), blk, 0, stream>>>(
        yb16, DI_, wop + (size_t)l * DM_ * DI_, DI_, nullptr, h,
        h, nullptr, DM_, DM_, DI_);

    k_ln<<<M, blk, 0, stream>>>(h, ln2_w + l * DM_, ln2_b + l * DM_, xln16);

    // ffh = gelu(xln @ ff_w1^T + b1) -> bf16  (M x 1536, K=768)
    k_gemm_mfma<2><<<dim3(2 * DM_ / 128, M / 128), blk, 0, stream>>>(
        xln16, DM_, wf1 + (size_t)l * 2 * DM_ * DM_, DM_, ff_b1 + l * 2 * DM_, nullptr,
        ffh16, nullptr, 2 * DM_, 2 * DM_, DM_);

    // h += ffh @ ff_w2^T + b2   (M x 768, K=1536)
    k_gemm_mfma<1><<<dim3(DM_ / 128, M / 128), blk, 0, stream>>>(
        ffh16, 2 * DM_, wf2 + (size_t)l * DM_ * 2 * DM_, 2 * DM_, ff_b2 + l * DM_, h,
        h, nullptr, DM_, DM_, DI_);
  }

  k_ln<<<M, blk, 0, stream>>>(h, lnf_w, lnf_b, xln16);
  k_head1<<<dim3(16, B_), blk, 0, stream>>>(xln16, w_head, part);
  k_head2<<<1, 64, 0, stream>>>(part, b_head, out);
}

// Round 6
// 639.700 us; speedup vs baseline: 4.4374x; 1.1631x over previous
//
#include <hip/hip_runtime.h>
#include <hip/hip_bf16.h>
#include <math.h>

#define B_ 4
#define S_ 512
#define DM_ 768
#define L_ 2
#define DI_ 1536
#define DS_ 16
#define KC_ 4
#define DTR_ 48
#define NSEG 8
#define TS 64
#define KSPLIT 8

typedef __hip_bfloat16 bf16;
typedef __attribute__((ext_vector_type(8))) short short8;
typedef __attribute__((ext_vector_type(4))) float f32x4;

#define GLDS16(g, l) __builtin_amdgcn_global_load_lds( \
    (const __attribute__((address_space(1))) void*)(g), \
    (__attribute__((address_space(3))) void*)(l), 16, 0, 0)

// ---------------- elementwise / small kernels ----------------

__global__ void k_embed(const float* __restrict__ x, const float* __restrict__ w_in,
                        const float* __restrict__ b_in, const float* __restrict__ pe,
                        float* __restrict__ h) {
  int idx = blockIdx.x * 256 + threadIdx.x;
  if (idx >= B_ * S_ * DM_) return;
  int d = idx % DM_;
  int t = idx / DM_;
  int s = t % S_;
  h[idx] = x[t] * w_in[d] + b_in[d] + pe[s * DM_ + d];
}

// LayerNorm over DM; fp32 in, bf16 out
__global__ void k_ln(const float* __restrict__ in, const float* __restrict__ w,
                     const float* __restrict__ b, bf16* __restrict__ out) {
  __shared__ float red1[4], red2[4];
  __shared__ float s_mu, s_rstd;
  int row = blockIdx.x;
  const float* x = in + (size_t)row * DM_;
  float s1 = 0.f, s2 = 0.f;
  for (int i = threadIdx.x; i < DM_; i += 256) { float v = x[i]; s1 += v; s2 += v * v; }
  for (int off = 32; off; off >>= 1) { s1 += __shfl_down(s1, off); s2 += __shfl_down(s2, off); }
  if ((threadIdx.x & 63) == 0) { red1[threadIdx.x >> 6] = s1; red2[threadIdx.x >> 6] = s2; }
  __syncthreads();
  if (threadIdx.x == 0) {
    float t1 = red1[0] + red1[1] + red1[2] + red1[3];
    float t2 = red2[0] + red2[1] + red2[2] + red2[3];
    float mu = t1 * (1.f / DM_);
    float var = t2 * (1.f / DM_) - mu * mu;
    s_mu = mu;
    s_rstd = rsqrtf(var + 1e-5f);
  }
  __syncthreads();
  float mu = s_mu, rstd = s_rstd;
  for (int i = threadIdx.x; i < DM_; i += 256)
    out[(size_t)row * DM_ + i] = __float2bfloat16((x[i] - mu) * rstd * w[i] + b[i]);
}

// all weight casts + A_log transpose in ONE launch (grid-stride)
__global__ void k_castall(const float* __restrict__ w_inproj, const float* __restrict__ w_outproj,
                          const float* __restrict__ ff_w1, const float* __restrict__ ff_w2,
                          const float* __restrict__ w_xproj, const float* __restrict__ w_dt,
                          const float* __restrict__ A_log,
                          bf16* __restrict__ wip, bf16* __restrict__ wop,
                          bf16* __restrict__ wf1, bf16* __restrict__ wf2,
                          bf16* __restrict__ wxp, bf16* __restrict__ wdtp,
                          float* __restrict__ At) {
  const int N0 = L_ * 2 * DI_ * DM_;          // wip  4718592
  const int N1 = L_ * DM_ * DI_;              // wop  2359296
  const int N2 = L_ * 2 * DM_ * DM_;          // wf1  2359296
  const int N3 = L_ * DM_ * 2 * DM_;          // wf2  2359296
  const int N4 = L_ * 128 * DI_;              // wxp   393216
  const int N5 = L_ * DI_ * 64;               // wdtp  196608
  const int N6 = L_ * 16 * DI_;               // At     49152
  const int TOT = N0 + N1 + N2 + N3 + N4 + N5 + N6;
  for (int i = blockIdx.x * 256 + threadIdx.x; i < TOT; i += gridDim.x * 256) {
    int j = i;
    if (j < N0) { wip[j] = __float2bfloat16(w_inproj[j]); continue; }
    j -= N0;
    if (j < N1) { wop[j] = __float2bfloat16(w_outproj[j]); continue; }
    j -= N1;
    if (j < N2) { wf1[j] = __float2bfloat16(ff_w1[j]); continue; }
    j -= N2;
    if (j < N3) { wf2[j] = __float2bfloat16(ff_w2[j]); continue; }
    j -= N3;
    if (j < N4) {
      int col = j % DI_;
      int row = (j / DI_) & 127;
      int l = j / (128 * DI_);
      float v = (row < 80) ? w_xproj[((size_t)l * 80 + row) * DI_ + col] : 0.f;
      wxp[j] = __float2bfloat16(v);
      continue;
    }
    j -= N4;
    if (j < N5) {
      int col = j & 63;
      int r = (j >> 6) % DI_;
      int l = j / (DI_ * 64);
      float v = (col < 48) ? w_dt[((size_t)l * DI_ + r) * 48 + col] : 0.f;
      wdtp[j] = __float2bfloat16(v);
      continue;
    }
    j -= N5;
    {
      int d = j % DI_;
      int n = (j / DI_) & 15;
      int l = j / (16 * DI_);
      At[j] = A_log[((size_t)l * DI_ + d) * 16 + n];
    }
  }
}

// depthwise causal conv (K=4) + bias + SiLU; writes fp32 xc and bf16 xcb
__global__ void k_conv_silu(const float* __restrict__ xz, const float* __restrict__ cw,
                            const float* __restrict__ cb, float* __restrict__ xc,
                            bf16* __restrict__ xcb) {
  int idx = blockIdx.x * 256 + threadIdx.x;
  if (idx >= B_ * S_ * DI_) return;
  int d = idx % DI_;
  int t = idx / DI_;
  int s = t % S_;
  int b = t / S_;
  float acc = cb[d];
  const float* base = xz + (size_t)(b * S_) * (2 * DI_) + d;
#pragma unroll
  for (int k = 0; k < KC_; ++k) {
    int ss = s - (KC_ - 1) + k;
    if (ss >= 0) acc = fmaf(base[(size_t)ss * (2 * DI_)], cw[d * KC_ + k], acc);
  }
  float v = acc / (1.f + expf(-acc));
  xc[idx] = v;
  xcb[idx] = __float2bfloat16(v);
}

// ---------------- segmented selective scan ----------------
// Pass A: one thread per d; 16 states in VGPRs; no LDS, no shuffles.
// At layout [l][n][DI] (coalesced). hend layout [b][seg][n][DI] (coalesced).
// ylocal aliases delta, cumd aliases xc: each thread reads [s,d] before writing
// the same [s,d] (same-thread program order -> safe).
__global__ __launch_bounds__(256)
void k_scanA(const float* __restrict__ delta, const float* __restrict__ xc,
             const float* __restrict__ bc, const float* __restrict__ At,
             const float* __restrict__ Dv,
             float* __restrict__ ylocal, float* __restrict__ cumd,
             float* __restrict__ hend) {
  int b = blockIdx.y;
  int seg = blockIdx.z;
  int d = blockIdx.x * 256 + threadIdx.x;
  int s0 = seg * TS;

  float A[16], hst[16];
#pragma unroll
  for (int n = 0; n < 16; ++n) {
    A[n] = -__expf(At[(size_t)n * DI_ + d]);
    hst[n] = 0.f;
  }
  float Dd = Dv[d];
  float cd = 0.f;

  const float* dp = delta + ((size_t)(b * S_ + s0)) * DI_ + d;
  const float* up = xc + ((size_t)(b * S_ + s0)) * DI_ + d;
  const float* bp = bc + ((size_t)(b * S_ + s0)) * 32;
  float* yp = ylocal + ((size_t)(b * S_ + s0)) * DI_ + d;
  float* cp = cumd + ((size_t)(b * S_ + s0)) * DI_ + d;

  float dl_next = dp[0];
  float u_next = up[0];
#pragma unroll 4
  for (int s = 0; s < TS; ++s) {
    float dl = dl_next, u = u_next;
    if (s + 1 < TS) {
      dl_next = dp[(size_t)(s + 1) * DI_];
      u_next = up[(size_t)(s + 1) * DI_];
    }
    cd += dl;
    float dlu = dl * u;
    float y = 0.f;
#pragma unroll
    for (int n = 0; n < 16; ++n) {
      float e = __expf(dl * A[n]);
      hst[n] = fmaf(hst[n], e, dlu * bp[s * 32 + n]);
      y = fmaf(hst[n], bp[s * 32 + 16 + n], y);
    }
    yp[(size_t)s * DI_] = fmaf(u, Dd, y);
    cp[(size_t)s * DI_] = cd;
  }
  float* hp = hend + ((size_t)(b * NSEG + seg) * 16) * DI_ + d;
#pragma unroll
  for (int n = 0; n < 16; ++n) hp[(size_t)n * DI_] = hst[n];
}

// Pass B: chain segment boundary states; layouts [b][seg][n][DI], d fastest -> coalesced
__global__ void k_scanB(const float* __restrict__ hend, const float* __restrict__ cumd,
                        const float* __restrict__ At, float* __restrict__ h0seg) {
  int idx = blockIdx.x * 256 + threadIdx.x;
  if (idx >= B_ * 16 * DI_) return;
  int d = idx % DI_;
  int r = idx / DI_;
  int n = r & 15;
  int b = r >> 4;
  float A = -__expf(At[(size_t)n * DI_ + d]);
  float h0 = 0.f;
  for (int seg = 0; seg < NSEG; ++seg) {
    size_t o = ((size_t)(b * NSEG + seg) * 16 + n) * DI_ + d;
    h0seg[o] = h0;
    float cdt = cumd[((size_t)(b * S_ + seg * TS + TS - 1)) * DI_ + d];
    h0 = h0 * __expf(A * cdt) + hend[o];
  }
}

// Pass C: y = (y_local + sum_n C[n]*exp(A_n*cumd)*h0seg[n]) * silu(z) -> bf16
__global__ __launch_bounds__(256)
void k_scanC(const float* __restrict__ ylocal, const float* __restrict__ cumd,
             const float* __restrict__ bc, const float* __restrict__ At,
             const float* __restrict__ h0seg, const float* __restrict__ xz,
             bf16* __restrict__ yb16) {
  int d = blockIdx.x * 256 + threadIdx.x;
  int t = blockIdx.y;
  int b = blockIdx.z;
  int seg = t / TS;
  size_t o = ((size_t)(b * S_ + t)) * DI_ + d;
  float y = ylocal[o];
  if (seg) {
    float cd = cumd[o];
    const float* Cp = bc + ((size_t)(b * S_ + t)) * 32 + 16;
    const float* Hb = h0seg + ((size_t)(b * NSEG + seg) * 16) * DI_ + d;
#pragma unroll
    for (int n = 0; n < 16; ++n)
      y += Cp[n] * __expf(-__expf(At[(size_t)n * DI_ + d]) * cd) * Hb[(size_t)n * DI_];
  }
  float z = xz[((size_t)(b * S_ + t)) * (2 * DI_) + DI_ + d];
  float sig = 1.f / (1.f + __expf(-z));
  yb16[o] = __float2bfloat16(y * (z * sig));
}

// head stage 1: block (j,b) reduces rows s in [j*32, j*32+32)
__global__ void k_head1(const bf16* __restrict__ hf, const float* __restrict__ wh,
                        float* __restrict__ partial) {
  __shared__ float red[4];
  int b = blockIdx.y, j = blockIdx.x;
  const bf16* base = hf + ((size_t)b * S_ + j * 32) * DM_;
  float acc = 0.f;
  for (int i = threadIdx.x; i < 32 * DM_; i += 256) {
    int dd = i - (i / DM_) * DM_;
    acc += __bfloat162float(base[i]) * wh[dd];
  }
  for (int off = 32; off; off >>= 1) acc += __shfl_down(acc, off);
  if ((threadIdx.x & 63) == 0) red[threadIdx.x >> 6] = acc;
  __syncthreads();
  if (threadIdx.x == 0)
    partial[b * 16 + j] = red[0] + red[1] + red[2] + red[3];
}

__global__ void k_head2(const float* __restrict__ partial, const float* __restrict__ bh,
                        float* __restrict__ out) {
  int b = threadIdx.x;
  if (b < B_) {
    float acc = 0.f;
    for (int j = 0; j < 16; ++j) acc += partial[b * 16 + j];
    out[b] = acc * (1.f / S_) + bh[0];
  }
}

// ---------------- MFMA GEMM, 2-phase double-buffered ----------------
// C[m,n] = epi( sum_k A[m,k]*W[n,k] ), A,W bf16 row-major (K contiguous).
// 128x128 tile, BK=32, double-buffered LDS, T3 "minimum 2-phase" schedule:
//   prologue STAGE(0); vmcnt(0); barrier
//   loop: STAGE(next) -> ds_read cur -> lgkmcnt(0) -> MFMA -> vmcnt(0); barrier
// EPI: 0 f32 out; 1 f32 out + bias? + res; 2 bias+gelu -> bf16; 3 bias+softplus -> f32;
//      5 split-K partial: out1 + blockIdx.z*2048*128 f32, K-chunk = blockIdx.z
template <int EPI>
__global__ __launch_bounds__(256)
void k_gemm_mfma(const bf16* __restrict__ A, int lda,
                 const bf16* __restrict__ W, int ldw,
                 const float* __restrict__ bias,
                 const float* __restrict__ res,
                 void* __restrict__ out1,
                 int ldc, int N, int Kdim) {
  __shared__ short As[2][128 * 32];
  __shared__ short Bs[2][128 * 32];
  int m0 = blockIdx.y * 128;
  int n0 = blockIdx.x * 128;
  int wid = threadIdx.x >> 6;
  int lane = threadIdx.x & 63;
  int wm = wid >> 1, wn = wid & 1;
  int lr = lane & 15;
  int kb = (lane >> 4) * 8;
  int koff = blockIdx.z * Kdim;

  f32x4 acc[4][4];
#pragma unroll
  for (int i = 0; i < 4; ++i)
#pragma unroll
    for (int j = 0; j < 4; ++j) {
      acc[i][j][0] = 0.f; acc[i][j][1] = 0.f; acc[i][j][2] = 0.f; acc[i][j][3] = 0.f;
    }

#define GSTAGE(bb, kt)                                                            \
  {                                                                               \
    int k0 = koff + (kt) * 32;                                                    \
    _Pragma("unroll")                                                             \
    for (int c0 = 0; c0 < 2; ++c0) {                                              \
      int c = c0 * 256 + threadIdx.x;                                             \
      GLDS16(A + (size_t)(m0 + (c >> 2)) * lda + k0 + (c & 3) * 8,                \
             (char*)&As[bb][0] + c * 16);                                         \
    }                                                                             \
    _Pragma("unroll")                                                             \
    for (int c0 = 0; c0 < 2; ++c0) {                                              \
      int c = c0 * 256 + threadIdx.x;                                             \
      GLDS16(W + (size_t)(n0 + (c >> 2)) * ldw + k0 + (c & 3) * 8,                \
             (char*)&Bs[bb][0] + c * 16);                                         \
    }                                                                             \
  }

  int nt = Kdim / 32;
  GSTAGE(0, 0);
  asm volatile("s_waitcnt vmcnt(0)" ::: "memory");
  __builtin_amdgcn_s_barrier();
  __builtin_amdgcn_sched_barrier(0);

  int cur = 0;
  for (int t = 0; t < nt; ++t) {
    if (t + 1 < nt) GSTAGE(cur ^ 1, t + 1);

    short8 a[4], b[4];
#pragma unroll
    for (int f = 0; f < 4; ++f) {
      a[f] = *(const short8*)&As[cur][(wm * 64 + f * 16 + lr) * 32 + kb];
      b[f] = *(const short8*)&Bs[cur][(wn * 64 + f * 16 + lr) * 32 + kb];
    }
    asm volatile("s_waitcnt lgkmcnt(0)" ::: "memory");
    __builtin_amdgcn_sched_barrier(0);
    __builtin_amdgcn_s_setprio(1);
#pragma unroll
    for (int i = 0; i < 4; ++i)
#pragma unroll
      for (int j = 0; j < 4; ++j)
        acc[i][j] = __builtin_amdgcn_mfma_f32_16x16x32_bf16(a[i], b[j], acc[i][j], 0, 0, 0);
    __builtin_amdgcn_s_setprio(0);
    __builtin_amdgcn_sched_barrier(0);
    asm volatile("s_waitcnt vmcnt(0)" ::: "memory");
    __builtin_amdgcn_s_barrier();
    __builtin_amdgcn_sched_barrier(0);
    cur ^= 1;
  }
#undef GSTAGE

#pragma unroll
  for (int i = 0; i < 4; ++i) {
#pragma unroll
    for (int j = 0; j < 4; ++j) {
      int nl = wn * 64 + j * 16 + (lane & 15);
      int n = n0 + nl;
#pragma unroll
      for (int q = 0; q < 4; ++q) {
        int m = m0 + wm * 64 + i * 16 + (lane >> 4) * 4 + q;
        float v = acc[i][j][q];
        if (EPI == 0) {
          if (n < N) ((float*)out1)[(size_t)m * ldc + n] = v;
        } else if (EPI == 1) {
          if (n < N) {
            if (bias) v += bias[n];
            ((float*)out1)[(size_t)m * ldc + n] = v + res[(size_t)m * ldc + n];
          }
        } else if (EPI == 2) {
          if (n < N) {
            v += bias[n];
            v = 0.5f * v * (1.f + erff(v * 0.70710678118654752f));
            ((bf16*)out1)[(size_t)m * ldc + n] = __float2bfloat16(v);
          }
        } else if (EPI == 3) {
          if (n < N) {
            v += bias[n];
            v = (v > 20.f) ? v : log1pf(expf(v));
            ((float*)out1)[(size_t)m * ldc + n] = v;
          }
        } else if (EPI == 5) {
          ((float*)out1)[(size_t)blockIdx.z * 2048 * 128 + (size_t)m * 128 + nl] = v;
        }
      }
    }
  }
}

// split-K reduce for xproj: sum 8 partials, emit dtp (bf16, K-padded 64) + bc (f32)
__global__ void k_xreduce(const float* __restrict__ pxp, bf16* __restrict__ dtp,
                          float* __restrict__ bcb) {
  int idx = blockIdx.x * 256 + threadIdx.x;
  if (idx >= 2048 * 128) return;
  int m = idx >> 7, n = idx & 127;
  float s = 0.f;
#pragma unroll
  for (int k = 0; k < KSPLIT; ++k) s += pxp[(size_t)k * 2048 * 128 + idx];
  if (n < 64) dtp[m * 64 + n] = __float2bfloat16(n < 48 ? s : 0.f);
  if (n >= 48 && n < 80) bcb[m * 32 + (n - 48)] = s;
}

// ---------------- launch ----------------

extern "C" void kernel_launch(void* const* d_in, const int* in_sizes, int n_in,
                              void* d_out, int out_size, void* d_ws, size_t ws_size,
                              hipStream_t stream) {
  const float* x        = (const float*)d_in[0];
  const float* w_in     = (const float*)d_in[1];
  const float* b_in     = (const float*)d_in[2];
  const float* pe       = (const float*)d_in[3];
  const float* ln1_w    = (const float*)d_in[4];
  const float* ln1_b    = (const float*)d_in[5];
  const float* w_inproj = (const float*)d_in[6];
  const float* conv_w   = (const float*)d_in[7];
  const float* conv_b   = (const float*)d_in[8];
  const float* w_xproj  = (const float*)d_in[9];
  const float* w_dt     = (const float*)d_in[10];
  const float* b_dt     = (const float*)d_in[11];
  const float* A_log    = (const float*)d_in[12];
  const float* Dv       = (const float*)d_in[13];
  const float* w_outproj= (const float*)d_in[14];
  const float* ln2_w    = (const float*)d_in[15];
  const float* ln2_b    = (const float*)d_in[16];
  const float* ff_w1    = (const float*)d_in[17];
  const float* ff_b1    = (const float*)d_in[18];
  const float* ff_w2    = (const float*)d_in[19];
  const float* ff_b2    = (const float*)d_in[20];
  const float* lnf_w    = (const float*)d_in[21];
  const float* lnf_b    = (const float*)d_in[22];
  const float* w_head   = (const float*)d_in[23];
  const float* b_head   = (const float*)d_in[24];
  float* out = (float*)d_out;

  const int M = B_ * S_;  // 2048

  float* wsf = (float*)d_ws;
  float* h    = wsf; wsf += (size_t)M * DM_;
  float* xz   = wsf; wsf += (size_t)M * 2 * DI_;
  float* xc   = wsf; wsf += (size_t)M * DI_;
  float* bc   = wsf; wsf += (size_t)M * 32;
  float* dlt  = wsf; wsf += (size_t)M * DI_;
  float* hend = wsf; wsf += (size_t)B_ * NSEG * DI_ * 16;
  float* h0sg = wsf; wsf += (size_t)B_ * NSEG * DI_ * 16;
  float* pxp  = wsf; wsf += (size_t)KSPLIT * 2048 * 128;
  float* At   = wsf; wsf += (size_t)L_ * 16 * DI_;
  float* part = wsf; wsf += 64;
  bf16* wsb = (bf16*)wsf;
  bf16* xln16 = wsb; wsb += (size_t)M * DM_;
  bf16* xcb   = wsb; wsb += (size_t)M * DI_;
  bf16* dtp   = wsb; wsb += (size_t)M * 64;
  bf16* yb16  = wsb; wsb += (size_t)M * DI_;
  bf16* ffh16 = wsb; wsb += (size_t)M * DI_;
  bf16* wip   = wsb; wsb += (size_t)L_ * 2 * DI_ * DM_;
  bf16* wxp   = wsb; wsb += (size_t)L_ * 128 * DI_;
  bf16* wdtp  = wsb; wsb += (size_t)L_ * DI_ * 64;
  bf16* wop   = wsb; wsb += (size_t)L_ * DM_ * DI_;
  bf16* wf1   = wsb; wsb += (size_t)L_ * 2 * DM_ * DM_;
  bf16* wf2   = wsb; wsb += (size_t)L_ * DM_ * 2 * DM_;

  // scan pass A outputs alias their own per-thread-read inputs (see k_scanA note)
  float* ylocal = dlt;
  float* cumd   = xc;

  dim3 blk(256);

  k_castall<<<2048, blk, 0, stream>>>(w_inproj, w_outproj, ff_w1, ff_w2,
                                      w_xproj, w_dt, A_log,
                                      wip, wop, wf1, wf2, wxp, wdtp, At);

  k_embed<<<(B_ * S_ * DM_ + 255) / 256, blk, 0, stream>>>(x, w_in, b_in, pe, h);

  for (int l = 0; l < L_; ++l) {
    const float* Atl = At + (size_t)l * 16 * DI_;

    k_ln<<<M, blk, 0, stream>>>(h, ln1_w + l * DM_, ln1_b + l * DM_, xln16);

    // xz = xln @ w_inproj^T   (M x 3072, K=768)
    k_gemm_mfma<0><<<dim3(2 * DI_ / 128, M / 128), blk, 0, stream>>>(
        xln16, DM_, wip + (size_t)l * 2 * DI_ * DM_, DM_, nullptr, nullptr,
        xz, 2 * DI_, 2 * DI_, DM_);

    k_conv_silu<<<(B_ * S_ * DI_ + 255) / 256, blk, 0, stream>>>(
        xz, conv_w + l * DI_ * KC_, conv_b + l * DI_, xc, xcb);

    // xproj split-K: partials (M x 128, K=1536 in 8 chunks of 192)
    k_gemm_mfma<5><<<dim3(1, M / 128, KSPLIT), blk, 0, stream>>>(
        xcb, DI_, wxp + (size_t)l * 128 * DI_, DI_, nullptr, nullptr,
        pxp, 0, 128, DI_ / KSPLIT);
    k_xreduce<<<(2048 * 128) / 256, blk, 0, stream>>>(pxp, dtp, bc);

    // delta = softplus(dtp @ wdtp^T + b_dt)   (M x 1536, K=64)
    k_gemm_mfma<3><<<dim3(DI_ / 128, M / 128), blk, 0, stream>>>(
        dtp, 64, wdtp + (size_t)l * DI_ * 64, 64, b_dt + l * DI_, nullptr,
        dlt, DI_, DI_, 64);

    // segmented scan: A (parallel local scans), B (boundary chain), C (correct+gate)
    k_scanA<<<dim3(DI_ / 256, B_, NSEG), blk, 0, stream>>>(
        dlt, xc, bc, Atl, Dv + l * DI_, ylocal, cumd, hend);
    k_scanB<<<(B_ * 16 * DI_ + 255) / 256, blk, 0, stream>>>(hend, cumd, Atl, h0sg);
    k_scanC<<<dim3(DI_ / 256, S_, B_), blk, 0, stream>>>(
        ylocal, cumd, bc, Atl, h0sg, xz, yb16);

    // h += yb @ w_outproj^T   (M x 768, K=1536)
    k_gemm_mfma<1><<<dim3(DM_ / 128, M / 128), blk, 0, stream>>>(
        yb16, DI_, wop + (size_t)l * DM_ * DI_, DI_, nullptr, h,
        h, DM_, DM_, DI_);

    k_ln<<<M, blk, 0, stream>>>(h, ln2_w + l * DM_, ln2_b + l * DM_, xln16);

    // ffh = gelu(xln @ ff_w1^T + b1) -> bf16  (M x 1536, K=768)
    k_gemm_mfma<2><<<dim3(2 * DM_ / 128, M / 128), blk, 0, stream>>>(
        xln16, DM_, wf1 + (size_t)l * 2 * DM_ * DM_, DM_, ff_b1 + l * 2 * DM_, nullptr,
        ffh16, 2 * DM_, 2 * DM_, DM_);

    // h += ffh @ ff_w2^T + b2   (M x 768, K=1536)
    k_gemm_mfma<1><<<dim3(DM_ / 128, M / 128), blk, 0, stream>>>(
        ffh16, 2 * DM_, wf2 + (size_t)l * DM_ * 2 * DM_, 2 * DM_, ff_b2 + l * DM_, h,
        h, DM_, DM_, DI_);
  }

  k_ln<<<M, blk, 0, stream>>>(h, lnf_w, lnf_b, xln16);
  k_head1<<<dim3(16, B_), blk, 0, stream>>>(xln16, w_head, part);
  k_head2<<<1, 64, 0, stream>>>(part, b_head, out);
}